// Round 9
// baseline (1155.766 us; speedup 1.0000x reference)
//
#include <hip/hip_runtime.h>
#include <cstddef>

#define NN 100000
#define NE 3200000
#define FIN 128
#define HID 16
#define NC 40
#define BNODES 128               // nodes per bucket
#define NBUK 782                 // ceil(NN/128)
#define CHUNK 4096               // edges per block in bucketing passes
#define NBLK_BKT ((NE + CHUNK - 1) / CHUNK)   // 782
#define NWAVE_G1 (NN / 16)       // 6250 waves, 16 nodes each
#define NBLK_G1 ((NWAVE_G1 + 3) / 4)          // 1563

typedef __attribute__((ext_vector_type(8))) short bf16x8;
typedef __attribute__((ext_vector_type(4))) float f32x4;

// ---- bf16 helpers (RNE pack, cheap unpack) ----
__device__ __forceinline__ unsigned bf16rne(float f) {
  unsigned u = __float_as_uint(f);
  return (u + 0x7fffu + ((u >> 16) & 1u)) >> 16;
}
__device__ __forceinline__ unsigned bfpack(float lo, float hi) {
  return bf16rne(lo) | (bf16rne(hi) << 16);
}
__device__ __forceinline__ float bflo(unsigned w) { return __uint_as_float(w << 16); }
__device__ __forceinline__ float bfhi(unsigned w) { return __uint_as_float(w & 0xffff0000u); }

// ---------- CSR-lite build: bucket histogram + scan + bucketize ----------

__global__ __launch_bounds__(256) void k_bcount(const int* __restrict__ ei,
                                                int* __restrict__ bcnt) {
  __shared__ int h[NBUK];
  int t = threadIdx.x;
  for (int i = t; i < NBUK; i += 256) h[i] = 0;
  __syncthreads();
  int base = blockIdx.x * CHUNK;
#pragma unroll
  for (int i = 0; i < 16; ++i) {
    int e = base + i * 256 + t;
    if (e < NE) atomicAdd(&h[ei[NE + e] >> 7], 1);
  }
  __syncthreads();
  for (int i = t; i < NBUK; i += 256)
    if (h[i]) atomicAdd(&bcnt[i], h[i]);
}

// Exclusive scan of NBUK bucket counts (single block, carry loop)
__global__ __launch_bounds__(256) void k_bscan(const int* __restrict__ bcnt,
    int* __restrict__ bbase, int* __restrict__ bcur) {
  __shared__ int scn[256];
  __shared__ int carry;
  int t = threadIdx.x;
  if (t == 0) carry = 0;
  __syncthreads();
  for (int c0 = 0; c0 < NBUK; c0 += 256) {
    int idx = c0 + t;
    int v = (idx < NBUK) ? bcnt[idx] : 0;
    scn[t] = v;
    __syncthreads();
    for (int st = 1; st < 256; st <<= 1) {
      int tmp = (t >= st) ? scn[t - st] : 0;
      __syncthreads();
      scn[t] += tmp;
      __syncthreads();
    }
    int ex = carry + scn[t] - v;
    if (idx < NBUK) { bbase[idx] = ex; bcur[idx] = ex; }
    __syncthreads();
    if (t == 255) carry += scn[255];
    __syncthreads();
  }
  if (t == 0) bbase[NBUK] = carry;
}

// Block-local counting sort into bucket streams.
// Record: .x = (dst&127)<<17 | src  (src < 2^17), .y = bits(u) full f32
__global__ __launch_bounds__(256) void k_bucketize(const int* __restrict__ ei,
    const float* __restrict__ ea, int* __restrict__ bcur,
    int2* __restrict__ bstream) {
  __shared__ int lh[NBUK];
  __shared__ int lbase[NBUK];
  __shared__ int gb[NBUK];
  __shared__ int scn[256];
  __shared__ int carry;
  __shared__ int meta[CHUNK];
  __shared__ int uval[CHUNK];
  __shared__ unsigned short sbkt[CHUNK];
  int t = threadIdx.x;
  for (int i = t; i < NBUK; i += 256) lh[i] = 0;
  if (t == 0) carry = 0;
  __syncthreads();
  int base = blockIdx.x * CHUNK;
  int rk[16], bk[16], mt[16], uv[16];
#pragma unroll
  for (int i = 0; i < 16; ++i) {
    int e = base + i * 256 + t;
    if (e < NE) {
      int d = ei[NE + e], sv = ei[e];
      int b = d >> 7;
      rk[i] = atomicAdd(&lh[b], 1);
      bk[i] = b;
      mt[i] = ((d & 127) << 17) | sv;
      uv[i] = __float_as_int(ea[e]);
    } else bk[i] = -1;
  }
  __syncthreads();
  // exclusive scan lh -> lbase (carry over 256-chunks)
  for (int c0 = 0; c0 < NBUK; c0 += 256) {
    int idx = c0 + t;
    int v = (idx < NBUK) ? lh[idx] : 0;
    scn[t] = v;
    __syncthreads();
    for (int st = 1; st < 256; st <<= 1) {
      int tmp = (t >= st) ? scn[t - st] : 0;
      __syncthreads();
      scn[t] += tmp;
      __syncthreads();
    }
    if (idx < NBUK) lbase[idx] = carry + scn[t] - v;
    __syncthreads();
    if (t == 255) carry += scn[255];
    __syncthreads();
  }
  int total = carry;
  for (int i = t; i < NBUK; i += 256)
    if (lh[i] > 0) gb[i] = atomicAdd(&bcur[i], lh[i]);
#pragma unroll
  for (int i = 0; i < 16; ++i) {
    if (bk[i] >= 0) {
      int p = lbase[bk[i]] + rk[i];
      meta[p] = mt[i];
      uval[p] = uv[i];
      sbkt[p] = (unsigned short)bk[i];
    }
  }
  __syncthreads();
  for (int s = t; s < total; s += 256) {
    int b = sbkt[s];
    bstream[gb[b] + (s - lbase[b])] = make_int2(meta[s], uval[s]);
  }
}

// ---------- dense kernel (MFMA, single XD table as in round 7) ----------

__global__ __launch_bounds__(256) void k_gemm1(const float* __restrict__ x,
    const float* __restrict__ W1, const float* __restrict__ root1,
    const float* __restrict__ bias1,
    unsigned* __restrict__ XD, float* __restrict__ XR) {
  int t = threadIdx.x;
  int l = t & 63;
  int wv = (blockIdx.x * 256 + t) >> 6;
  int nb = wv * 16;
  if (nb >= NN) return;
  int j16 = l & 15, kg = l >> 4;

  bf16x8 bfrag[3][4];
  const float* wsrc0 = W1;
  const float* wsrc1 = W1 + 2048;
  const float* wsrc2 = root1;
#pragma unroll
  for (int kk = 0; kk < 4; ++kk) {
    int krow = kk * 32 + kg * 8;
#pragma unroll
    for (int b = 0; b < 8; ++b) {
      int o = (krow + b) * 16 + j16;
      bfrag[0][kk][b] = (short)bf16rne(wsrc0[o]);
      bfrag[1][kk][b] = (short)bf16rne(wsrc1[o]);
      bfrag[2][kk][b] = (short)bf16rne(wsrc2[o]);
    }
  }

  f32x4 acc0 = {0.f, 0.f, 0.f, 0.f};
  f32x4 acc1 = {0.f, 0.f, 0.f, 0.f};
  f32x4 acc2 = {0.f, 0.f, 0.f, 0.f};
  const float* xrow = x + (size_t)(nb + j16) * FIN + kg * 8;
#pragma unroll
  for (int kk = 0; kk < 4; ++kk) {
    float4 xa = *(const float4*)(xrow + kk * 32);
    float4 xb = *(const float4*)(xrow + kk * 32 + 4);
    bf16x8 a;
    a[0] = (short)bf16rne(xa.x); a[1] = (short)bf16rne(xa.y);
    a[2] = (short)bf16rne(xa.z); a[3] = (short)bf16rne(xa.w);
    a[4] = (short)bf16rne(xb.x); a[5] = (short)bf16rne(xb.y);
    a[6] = (short)bf16rne(xb.z); a[7] = (short)bf16rne(xb.w);
    acc0 = __builtin_amdgcn_mfma_f32_16x16x32_bf16(a, bfrag[0][kk], acc0, 0, 0, 0);
    acc1 = __builtin_amdgcn_mfma_f32_16x16x32_bf16(a, bfrag[1][kk], acc1, 0, 0, 0);
    acc2 = __builtin_amdgcn_mfma_f32_16x16x32_bf16(a, bfrag[2][kk], acc2, 0, 0, 0);
  }

  float bb = bias1[j16];
#pragma unroll
  for (int r = 0; r < 4; ++r) {
    int n = nb + kg * 4 + r;
    size_t idx = (size_t)n * HID + j16;
    XD[idx] = bfpack(acc0[r], acc1[r] - acc0[r]);
    XR[idx] = acc2[r] + bb;
  }
}

// ---------- edge-parallel fused aggregation ----------

// Layer-1: per-bucket LDS f32 accumulate of X0[s]+u*D[s], then mean+root+ELU -> Hb
__global__ __launch_bounds__(256) void k_agg1(const int2* __restrict__ bstream,
    const int* __restrict__ bbase, const unsigned* __restrict__ XD,
    const float* __restrict__ XR, unsigned* __restrict__ Hb,
    int* __restrict__ deg) {
  __shared__ float acc[BNODES * 17];   // stride 17: random-dst atomics spread banks
  __shared__ int cnt[BNODES];
  int b = blockIdx.x, t = threadIdx.x;
  for (int i = t; i < BNODES * 17; i += 256) acc[i] = 0.f;
  if (t < BNODES) cnt[t] = 0;
  __syncthreads();
  int s0 = bbase[b], s1 = bbase[b + 1];
  for (int i = s0 + t; i < s1; i += 256) {
    int2 r = bstream[i];
    int s = r.x & 131071;
    int ld = r.x >> 17;
    float u = __int_as_float(r.y);
    const uint4* wp = (const uint4*)(XD + (size_t)s * 16);
    uint4 w0 = wp[0], w1 = wp[1], w2 = wp[2], w3 = wp[3];
    float* ap = &acc[ld * 17];
    atomicAdd(ap + 0,  bflo(w0.x) + u * bfhi(w0.x));
    atomicAdd(ap + 1,  bflo(w0.y) + u * bfhi(w0.y));
    atomicAdd(ap + 2,  bflo(w0.z) + u * bfhi(w0.z));
    atomicAdd(ap + 3,  bflo(w0.w) + u * bfhi(w0.w));
    atomicAdd(ap + 4,  bflo(w1.x) + u * bfhi(w1.x));
    atomicAdd(ap + 5,  bflo(w1.y) + u * bfhi(w1.y));
    atomicAdd(ap + 6,  bflo(w1.z) + u * bfhi(w1.z));
    atomicAdd(ap + 7,  bflo(w1.w) + u * bfhi(w1.w));
    atomicAdd(ap + 8,  bflo(w2.x) + u * bfhi(w2.x));
    atomicAdd(ap + 9,  bflo(w2.y) + u * bfhi(w2.y));
    atomicAdd(ap + 10, bflo(w2.z) + u * bfhi(w2.z));
    atomicAdd(ap + 11, bflo(w2.w) + u * bfhi(w2.w));
    atomicAdd(ap + 12, bflo(w3.x) + u * bfhi(w3.x));
    atomicAdd(ap + 13, bflo(w3.y) + u * bfhi(w3.y));
    atomicAdd(ap + 14, bflo(w3.z) + u * bfhi(w3.z));
    atomicAdd(ap + 15, bflo(w3.w) + u * bfhi(w3.w));
    atomicAdd(&cnt[ld], 1);
  }
  __syncthreads();
  int nb = b * BNODES;
  for (int i = t; i < BNODES * 8; i += 256) {
    int ln = i >> 3, pr = i & 7;
    int n = nb + ln;
    if (n >= NN) continue;
    float ic = 1.0f / fmaxf((float)cnt[ln], 1.0f);
    int c0 = pr * 2;
    float h0 = acc[ln * 17 + c0]     * ic + XR[(size_t)n * HID + c0];
    float h1 = acc[ln * 17 + c0 + 1] * ic + XR[(size_t)n * HID + c0 + 1];
    h0 = h0 > 0.f ? h0 : expm1f(h0);
    h1 = h1 > 0.f ? h1 : expm1f(h1);
    Hb[(size_t)n * 8 + pr] = bfpack(h0, h1);
    if (pr == 0) deg[n] = cnt[ln];
  }
}

// Layer-2: per-bucket LDS accumulate of (1-u)*H[s] and u*H[s] -> A0, A1 (f32)
__global__ __launch_bounds__(256) void k_agg2(const int2* __restrict__ bstream,
    const int* __restrict__ bbase, const unsigned* __restrict__ Hb,
    float* __restrict__ A0, float* __restrict__ A1) {
  __shared__ float a0s[BNODES * 17];
  __shared__ float a1s[BNODES * 17];
  int b = blockIdx.x, t = threadIdx.x;
  for (int i = t; i < BNODES * 17; i += 256) { a0s[i] = 0.f; a1s[i] = 0.f; }
  __syncthreads();
  int s0 = bbase[b], s1 = bbase[b + 1];
  for (int i = s0 + t; i < s1; i += 256) {
    int2 r = bstream[i];
    int s = r.x & 131071;
    int ld = r.x >> 17;
    float u = __int_as_float(r.y);
    const uint4* hp = (const uint4*)(Hb + (size_t)s * 8);
    uint4 w0 = hp[0], w1 = hp[1];
    float* p0 = &a0s[ld * 17];
    float* p1 = &a1s[ld * 17];
    float h;
    h = bflo(w0.x); atomicAdd(p0 + 0, h - u * h); atomicAdd(p1 + 0, u * h);
    h = bfhi(w0.x); atomicAdd(p0 + 1, h - u * h); atomicAdd(p1 + 1, u * h);
    h = bflo(w0.y); atomicAdd(p0 + 2, h - u * h); atomicAdd(p1 + 2, u * h);
    h = bfhi(w0.y); atomicAdd(p0 + 3, h - u * h); atomicAdd(p1 + 3, u * h);
    h = bflo(w0.z); atomicAdd(p0 + 4, h - u * h); atomicAdd(p1 + 4, u * h);
    h = bfhi(w0.z); atomicAdd(p0 + 5, h - u * h); atomicAdd(p1 + 5, u * h);
    h = bflo(w0.w); atomicAdd(p0 + 6, h - u * h); atomicAdd(p1 + 6, u * h);
    h = bfhi(w0.w); atomicAdd(p0 + 7, h - u * h); atomicAdd(p1 + 7, u * h);
    h = bflo(w1.x); atomicAdd(p0 + 8, h - u * h); atomicAdd(p1 + 8, u * h);
    h = bfhi(w1.x); atomicAdd(p0 + 9, h - u * h); atomicAdd(p1 + 9, u * h);
    h = bflo(w1.y); atomicAdd(p0 + 10, h - u * h); atomicAdd(p1 + 10, u * h);
    h = bfhi(w1.y); atomicAdd(p0 + 11, h - u * h); atomicAdd(p1 + 11, u * h);
    h = bflo(w1.z); atomicAdd(p0 + 12, h - u * h); atomicAdd(p1 + 12, u * h);
    h = bfhi(w1.z); atomicAdd(p0 + 13, h - u * h); atomicAdd(p1 + 13, u * h);
    h = bflo(w1.w); atomicAdd(p0 + 14, h - u * h); atomicAdd(p1 + 14, u * h);
    h = bfhi(w1.w); atomicAdd(p0 + 15, h - u * h); atomicAdd(p1 + 15, u * h);
  }
  __syncthreads();
  int nb = b * BNODES;
  for (int i = t; i < BNODES * 16; i += 256) {
    int ln = i >> 4, ch = i & 15;
    int n = nb + ln;
    if (n >= NN) continue;
    A0[(size_t)n * HID + ch] = a0s[ln * 17 + ch];
    A1[(size_t)n * HID + ch] = a1s[ln * 17 + ch];
  }
}

// K5: out = log_softmax( (A0@W2[0] + A1@W2[1])/max(deg,1) + H@root2 + bias2 )
__global__ __launch_bounds__(256) void k_final(const float* __restrict__ A0,
    const float* __restrict__ A1, const unsigned* __restrict__ Hb,
    const int* __restrict__ deg, const float* __restrict__ W2,
    const float* __restrict__ root2, const float* __restrict__ bias2,
    float* __restrict__ out) {
  int t = threadIdx.x;
  int l = t & 63;
  int j = (l < NC) ? l : 0;
  float w0r[HID], w1r[HID], rr[HID];
#pragma unroll
  for (int k = 0; k < HID; ++k) {
    w0r[k] = W2[k * NC + j];
    w1r[k] = W2[HID * NC + k * NC + j];
    rr[k]  = root2[k * NC + j];
  }
  float b2 = bias2[j];
  int wid = (blockIdx.x * 256 + t) >> 6;
  int nwaves = gridDim.x * 4;
  for (int n0 = wid; n0 < NN; n0 += nwaves) {
    int n = __builtin_amdgcn_readfirstlane(n0);
    const float* a0p = A0 + (size_t)n * HID;
    const float* a1p = A1 + (size_t)n * HID;
    const unsigned* hp = Hb + (size_t)n * 8;
    float ic = 1.0f / fmaxf((float)deg[n], 1.0f);
    float accm = 0.f, accr = 0.f;
#pragma unroll
    for (int k = 0; k < HID; ++k) {
      accm += a0p[k] * w0r[k];
      accm += a1p[k] * w1r[k];
      unsigned hw = hp[k >> 1];
      float hk = (k & 1) ? bfhi(hw) : bflo(hw);
      accr += hk * rr[k];
    }
    float logit = accm * ic + accr + b2;
    float mx = (l < NC) ? logit : -INFINITY;
#pragma unroll
    for (int o = 32; o >= 1; o >>= 1) mx = fmaxf(mx, __shfl_xor(mx, o));
    float p = (l < NC) ? __expf(logit - mx) : 0.f;
    float sm = p;
#pragma unroll
    for (int o = 32; o >= 1; o >>= 1) sm += __shfl_xor(sm, o);
    if (l < NC) out[(size_t)n * NC + l] = logit - mx - __logf(sm);
  }
}

extern "C" void kernel_launch(void* const* d_in, const int* in_sizes, int n_in,
                              void* d_out, int out_size, void* d_ws, size_t ws_size,
                              hipStream_t stream) {
  const float* x     = (const float*)d_in[0];
  const int*   ei    = (const int*)d_in[1];
  const float* ea    = (const float*)d_in[2];
  const float* W1    = (const float*)d_in[3];
  const float* root1 = (const float*)d_in[4];
  const float* bias1 = (const float*)d_in[5];
  const float* W2    = (const float*)d_in[6];
  const float* root2 = (const float*)d_in[7];
  const float* bias2 = (const float*)d_in[8];
  float* out = (float*)d_out;
  char* base = (char*)d_ws;

  // Layout (bytes):
  //   [0,       6.4M)  XD  (u32[NN*16], bf16 X0|D pairs)  -> A0 (f32) after agg1
  //   [6.4M,   12.8M)  XR  (f32[NN*16])                   -> A1 (f32) after agg1
  //   [12.8M,  16.0M)  Hb  (u32[NN*8],  bf16 H pairs)
  //   [16.0M,  41.6M)  bstream (int2[NE])  — live through agg2
  //   [41.6M,  42.0M)  deg (int[NN])
  //   [42.0M, ...)     bcnt[NBUK], bbase[NBUK+1], bcur[NBUK]
  unsigned* XD = (unsigned*)base;
  float*    XR = (float*)(base + 6400000);
  unsigned* Hb = (unsigned*)(base + 12800000);
  float*    A0 = (float*)base;
  float*    A1 = (float*)(base + 6400000);
  int2*     bstream = (int2*)(base + 16000000);
  int*      deg   = (int*)(base + 41600000);
  int*      bcnt  = (int*)(base + 42000000);
  int*      bbase = bcnt + NBUK;
  int*      bcur  = bbase + NBUK + 1;

  hipMemsetAsync(bcnt, 0, NBUK * sizeof(int), stream);

  k_bcount<<<NBLK_BKT, 256, 0, stream>>>(ei, bcnt);
  k_bscan<<<1, 256, 0, stream>>>(bcnt, bbase, bcur);
  k_bucketize<<<NBLK_BKT, 256, 0, stream>>>(ei, ea, bcur, bstream);
  k_gemm1<<<NBLK_G1, 256, 0, stream>>>(x, W1, root1, bias1, XD, XR);
  k_agg1<<<NBUK, 256, 0, stream>>>(bstream, bbase, XD, XR, Hb, deg);
  k_agg2<<<NBUK, 256, 0, stream>>>(bstream, bbase, Hb, A0, A1);
  k_final<<<1024, 256, 0, stream>>>(A0, A1, Hb, deg, W2, root2, bias2, out);
}

// Round 10
// 227.331 us; speedup vs baseline: 5.0841x; 5.0841x over previous
//
#include <hip/hip_runtime.h>
#include <cstddef>

#define NN 100000
#define NE 3200000
#define FIN 128
#define HID 16
#define NC 40
#define NBUK 196                 // ceil(100000 / 512) node-range buckets
#define CHUNK 4096               // edges per block in bucketing passes
#define NBLK_BKT ((NE + CHUNK - 1) / CHUNK)   // 782
#define NWAVE_G1 (NN / 16)       // 6250 waves, 16 nodes each
#define NBLK_G1 ((NWAVE_G1 + 3) / 4)          // 1563

typedef __attribute__((ext_vector_type(8))) short bf16x8;
typedef __attribute__((ext_vector_type(4))) float f32x4;

// ---- bf16 helpers (RNE pack, cheap unpack) ----
__device__ __forceinline__ unsigned bf16rne(float f) {
  unsigned u = __float_as_uint(f);
  return (u + 0x7fffu + ((u >> 16) & 1u)) >> 16;
}
__device__ __forceinline__ unsigned bfpack(float lo, float hi) {
  return bf16rne(lo) | (bf16rne(hi) << 16);
}
__device__ __forceinline__ float bflo(unsigned w) { return __uint_as_float(w << 16); }
__device__ __forceinline__ float bfhi(unsigned w) { return __uint_as_float(w & 0xffff0000u); }

// ---------- CSR build: bucketed counting sort (atomic-light) ----------

__global__ __launch_bounds__(256) void k_bcount(const int* __restrict__ ei,
                                                int* __restrict__ bcnt) {
  __shared__ int h[NBUK];
  int t = threadIdx.x;
  for (int i = t; i < NBUK; i += 256) h[i] = 0;
  __syncthreads();
  int base = blockIdx.x * CHUNK;
#pragma unroll
  for (int i = 0; i < 16; ++i) {
    int e = base + i * 256 + t;
    if (e < NE) atomicAdd(&h[ei[NE + e] >> 9], 1);
  }
  __syncthreads();
  for (int i = t; i < NBUK; i += 256)
    if (h[i]) atomicAdd(&bcnt[i], h[i]);
}

__global__ __launch_bounds__(256) void k_bscan(const int* __restrict__ bcnt,
    int* __restrict__ bbase, int* __restrict__ bcur) {
  __shared__ int scn[256];
  int t = threadIdx.x;
  int v = (t < NBUK) ? bcnt[t] : 0;
  scn[t] = v;
  __syncthreads();
  for (int st = 1; st < 256; st <<= 1) {
    int tmp = (t >= st) ? scn[t - st] : 0;
    __syncthreads();
    scn[t] += tmp;
    __syncthreads();
  }
  if (t < NBUK) { int ex = scn[t] - v; bbase[t] = ex; bcur[t] = ex; }
  if (t == NBUK - 1) bbase[NBUK] = scn[t];
}

// Record: .x = (dst&511)<<17 | src   (src < 2^17), .y = bits(u)
__global__ __launch_bounds__(256) void k_bucketize(const int* __restrict__ ei,
    const float* __restrict__ ea, int* __restrict__ bcur,
    int2* __restrict__ bstream) {
  __shared__ int lh[NBUK];
  __shared__ int lbase[NBUK];
  __shared__ int gb[NBUK];
  __shared__ int scn[256];
  __shared__ int meta[CHUNK];
  __shared__ int uval[CHUNK];
  __shared__ unsigned char sbkt[CHUNK];
  int t = threadIdx.x;
  for (int i = t; i < NBUK; i += 256) lh[i] = 0;
  __syncthreads();
  int base = blockIdx.x * CHUNK;
  int rk[16], bk[16], mt[16], uv[16];
#pragma unroll
  for (int i = 0; i < 16; ++i) {
    int e = base + i * 256 + t;
    if (e < NE) {
      int d = ei[NE + e], sv = ei[e];
      int b = d >> 9;
      rk[i] = atomicAdd(&lh[b], 1);
      bk[i] = b;
      mt[i] = ((d & 511) << 17) | sv;
      uv[i] = __float_as_int(ea[e]);
    } else bk[i] = -1;
  }
  __syncthreads();
  int v = (t < NBUK) ? lh[t] : 0;
  scn[t] = v;
  __syncthreads();
  for (int st = 1; st < 256; st <<= 1) {
    int tmp = (t >= st) ? scn[t - st] : 0;
    __syncthreads();
    scn[t] += tmp;
    __syncthreads();
  }
  if (t < NBUK) lbase[t] = scn[t] - v;
  int total = scn[255];
  __syncthreads();
  if (t < NBUK && lh[t] > 0) gb[t] = atomicAdd(&bcur[t], lh[t]);
  __syncthreads();
#pragma unroll
  for (int i = 0; i < 16; ++i) {
    if (bk[i] >= 0) {
      int p = lbase[bk[i]] + rk[i];
      meta[p] = mt[i];
      uval[p] = uv[i];
      sbkt[p] = (unsigned char)bk[i];
    }
  }
  __syncthreads();
  for (int s = t; s < total; s += 256) {
    int b = sbkt[s];
    bstream[gb[b] + (s - lbase[b])] = make_int2(meta[s], uval[s]);
  }
}

// Pass D: one block per bucket -> off[] + packed sedge (src | u15<<17)
__global__ __launch_bounds__(512) void k_csr(const int2* __restrict__ bstream,
    const int* __restrict__ bbase, int* __restrict__ off,
    unsigned* __restrict__ sedge) {
  __shared__ int cnt[512];
  __shared__ int scn[512];
  __shared__ int cur[512];
  int b = blockIdx.x, t = threadIdx.x;
  int s0 = bbase[b], s1 = bbase[b + 1];
  cnt[t] = 0;
  __syncthreads();
  for (int i = s0 + t; i < s1; i += 512)
    atomicAdd(&cnt[bstream[i].x >> 17], 1);
  __syncthreads();
  int v = cnt[t];
  scn[t] = v;
  __syncthreads();
  for (int st = 1; st < 512; st <<= 1) {
    int tmp = (t >= st) ? scn[t - st] : 0;
    __syncthreads();
    scn[t] += tmp;
    __syncthreads();
  }
  int n = (b << 9) + t;
  if (n < NN) off[n] = s0 + scn[t];          // inclusive row-end
  cur[t] = s0 + scn[t] - v;                  // row start cursor
  __syncthreads();
  for (int i = s0 + t; i < s1; i += 512) {
    int2 r = bstream[i];
    int local = r.x >> 17;
    int pos = atomicAdd(&cur[local], 1);
    unsigned u15 = (unsigned)__float2int_rn(__int_as_float(r.y) * 32767.0f);
    sedge[pos] = (unsigned)(r.x & 131071) | (u15 << 17);
  }
}

// ---------- dense / pull kernels ----------

// K1 (MFMA): one wave computes 16 nodes x 48 cols of x @ [W1[0]|W1[1]|root1].
__global__ __launch_bounds__(256) void k_gemm1(const float* __restrict__ x,
    const float* __restrict__ W1, const float* __restrict__ root1,
    const float* __restrict__ bias1,
    unsigned* __restrict__ XD, float* __restrict__ XR) {
  int t = threadIdx.x;
  int l = t & 63;
  int wv = (blockIdx.x * 256 + t) >> 6;
  int nb = wv * 16;
  if (nb >= NN) return;
  int j16 = l & 15, kg = l >> 4;

  bf16x8 bfrag[3][4];
  const float* wsrc0 = W1;
  const float* wsrc1 = W1 + 2048;
  const float* wsrc2 = root1;
#pragma unroll
  for (int kk = 0; kk < 4; ++kk) {
    int krow = kk * 32 + kg * 8;
#pragma unroll
    for (int b = 0; b < 8; ++b) {
      int o = (krow + b) * 16 + j16;
      bfrag[0][kk][b] = (short)bf16rne(wsrc0[o]);
      bfrag[1][kk][b] = (short)bf16rne(wsrc1[o]);
      bfrag[2][kk][b] = (short)bf16rne(wsrc2[o]);
    }
  }

  f32x4 acc0 = {0.f, 0.f, 0.f, 0.f};
  f32x4 acc1 = {0.f, 0.f, 0.f, 0.f};
  f32x4 acc2 = {0.f, 0.f, 0.f, 0.f};
  const float* xrow = x + (size_t)(nb + j16) * FIN + kg * 8;
#pragma unroll
  for (int kk = 0; kk < 4; ++kk) {
    float4 xa = *(const float4*)(xrow + kk * 32);
    float4 xb = *(const float4*)(xrow + kk * 32 + 4);
    bf16x8 a;
    a[0] = (short)bf16rne(xa.x); a[1] = (short)bf16rne(xa.y);
    a[2] = (short)bf16rne(xa.z); a[3] = (short)bf16rne(xa.w);
    a[4] = (short)bf16rne(xb.x); a[5] = (short)bf16rne(xb.y);
    a[6] = (short)bf16rne(xb.z); a[7] = (short)bf16rne(xb.w);
    acc0 = __builtin_amdgcn_mfma_f32_16x16x32_bf16(a, bfrag[0][kk], acc0, 0, 0, 0);
    acc1 = __builtin_amdgcn_mfma_f32_16x16x32_bf16(a, bfrag[1][kk], acc1, 0, 0, 0);
    acc2 = __builtin_amdgcn_mfma_f32_16x16x32_bf16(a, bfrag[2][kk], acc2, 0, 0, 0);
  }

  float bb = bias1[j16];
#pragma unroll
  for (int r = 0; r < 4; ++r) {
    int n = nb + kg * 4 + r;
    size_t idx = (size_t)n * HID + j16;
    XD[idx] = bfpack(acc0[r], acc1[r] - acc0[r]);
    XR[idx] = acc2[r] + bb;
  }
}

// Pull pass 1:  Hb[n] = bf16(elu(mean_e(X0[s]+u*D[s]) + XR[n]))
// Edge loop unrolled x4: 4 independent gathers in flight per thread.
__global__ __launch_bounds__(256) void k_pull1(const int* __restrict__ off,
    const unsigned* __restrict__ sedge, const unsigned* __restrict__ XD,
    const float* __restrict__ XR, unsigned* __restrict__ Hb) {
  int tid = blockIdx.x * 256 + threadIdx.x;
  int n = tid >> 2, c = tid & 3;
  if (n >= NN) return;
  int start = (n == 0) ? 0 : off[n - 1];
  int end = off[n];
  float4 acc = make_float4(0.f, 0.f, 0.f, 0.f);
  int i = start;
  for (; i + 4 <= end; i += 4) {
    unsigned se0 = sedge[i], se1 = sedge[i + 1];
    unsigned se2 = sedge[i + 2], se3 = sedge[i + 3];
    uint4 w0 = *(const uint4*)(XD + (size_t)(se0 & 131071u) * HID + c * 4);
    uint4 w1 = *(const uint4*)(XD + (size_t)(se1 & 131071u) * HID + c * 4);
    uint4 w2 = *(const uint4*)(XD + (size_t)(se2 & 131071u) * HID + c * 4);
    uint4 w3 = *(const uint4*)(XD + (size_t)(se3 & 131071u) * HID + c * 4);
    float u0 = (float)(se0 >> 17) * (1.0f / 32767.0f);
    float u1 = (float)(se1 >> 17) * (1.0f / 32767.0f);
    float u2 = (float)(se2 >> 17) * (1.0f / 32767.0f);
    float u3 = (float)(se3 >> 17) * (1.0f / 32767.0f);
    acc.x += bflo(w0.x) + u0 * bfhi(w0.x);
    acc.y += bflo(w0.y) + u0 * bfhi(w0.y);
    acc.z += bflo(w0.z) + u0 * bfhi(w0.z);
    acc.w += bflo(w0.w) + u0 * bfhi(w0.w);
    acc.x += bflo(w1.x) + u1 * bfhi(w1.x);
    acc.y += bflo(w1.y) + u1 * bfhi(w1.y);
    acc.z += bflo(w1.z) + u1 * bfhi(w1.z);
    acc.w += bflo(w1.w) + u1 * bfhi(w1.w);
    acc.x += bflo(w2.x) + u2 * bfhi(w2.x);
    acc.y += bflo(w2.y) + u2 * bfhi(w2.y);
    acc.z += bflo(w2.z) + u2 * bfhi(w2.z);
    acc.w += bflo(w2.w) + u2 * bfhi(w2.w);
    acc.x += bflo(w3.x) + u3 * bfhi(w3.x);
    acc.y += bflo(w3.y) + u3 * bfhi(w3.y);
    acc.z += bflo(w3.z) + u3 * bfhi(w3.z);
    acc.w += bflo(w3.w) + u3 * bfhi(w3.w);
  }
  for (; i < end; ++i) {
    unsigned se = sedge[i];
    int s = se & 131071u;
    float u = (float)(se >> 17) * (1.0f / 32767.0f);
    uint4 w = *(const uint4*)(XD + (size_t)s * HID + c * 4);
    acc.x += bflo(w.x) + u * bfhi(w.x);
    acc.y += bflo(w.y) + u * bfhi(w.y);
    acc.z += bflo(w.z) + u * bfhi(w.z);
    acc.w += bflo(w.w) + u * bfhi(w.w);
  }
  float ic = 1.0f / fmaxf((float)(end - start), 1.0f);
  float4 r = *(const float4*)(XR + (size_t)n * HID + c * 4);
  float4 h;
  h.x = acc.x * ic + r.x;
  h.y = acc.y * ic + r.y;
  h.z = acc.z * ic + r.z;
  h.w = acc.w * ic + r.w;
  h.x = h.x > 0.f ? h.x : expm1f(h.x);
  h.y = h.y > 0.f ? h.y : expm1f(h.y);
  h.z = h.z > 0.f ? h.z : expm1f(h.z);
  h.w = h.w > 0.f ? h.w : expm1f(h.w);
  uint2 hw;
  hw.x = bfpack(h.x, h.y);
  hw.y = bfpack(h.z, h.w);
  *(uint2*)(Hb + (size_t)n * 8 + c * 2) = hw;
}

// Pull pass 2: A0[n] = sum (1-u)*H[s];  A1[n] = sum u*H[s]   (f32 out)
// Edge loop unrolled x4.
__global__ __launch_bounds__(256) void k_pull2(const int* __restrict__ off,
    const unsigned* __restrict__ sedge, const unsigned* __restrict__ Hb,
    float* __restrict__ A0, float* __restrict__ A1) {
  int tid = blockIdx.x * 256 + threadIdx.x;
  int n = tid >> 2, c = tid & 3;
  if (n >= NN) return;
  int start = (n == 0) ? 0 : off[n - 1];
  int end = off[n];
  float4 a0 = make_float4(0.f, 0.f, 0.f, 0.f);
  float4 a1 = make_float4(0.f, 0.f, 0.f, 0.f);
  int i = start;
  for (; i + 4 <= end; i += 4) {
    unsigned se0 = sedge[i], se1 = sedge[i + 1];
    unsigned se2 = sedge[i + 2], se3 = sedge[i + 3];
    uint2 w0 = *(const uint2*)(Hb + (size_t)(se0 & 131071u) * 8 + c * 2);
    uint2 w1 = *(const uint2*)(Hb + (size_t)(se1 & 131071u) * 8 + c * 2);
    uint2 w2 = *(const uint2*)(Hb + (size_t)(se2 & 131071u) * 8 + c * 2);
    uint2 w3 = *(const uint2*)(Hb + (size_t)(se3 & 131071u) * 8 + c * 2);
    float u0 = (float)(se0 >> 17) * (1.0f / 32767.0f);
    float u1 = (float)(se1 >> 17) * (1.0f / 32767.0f);
    float u2 = (float)(se2 >> 17) * (1.0f / 32767.0f);
    float u3 = (float)(se3 >> 17) * (1.0f / 32767.0f);
    float h0, h1, h2, h3;
    h0 = bflo(w0.x); h1 = bfhi(w0.x); h2 = bflo(w0.y); h3 = bfhi(w0.y);
    a0.x += h0 - u0 * h0;  a1.x += u0 * h0;
    a0.y += h1 - u0 * h1;  a1.y += u0 * h1;
    a0.z += h2 - u0 * h2;  a1.z += u0 * h2;
    a0.w += h3 - u0 * h3;  a1.w += u0 * h3;
    h0 = bflo(w1.x); h1 = bfhi(w1.x); h2 = bflo(w1.y); h3 = bfhi(w1.y);
    a0.x += h0 - u1 * h0;  a1.x += u1 * h0;
    a0.y += h1 - u1 * h1;  a1.y += u1 * h1;
    a0.z += h2 - u1 * h2;  a1.z += u1 * h2;
    a0.w += h3 - u1 * h3;  a1.w += u1 * h3;
    h0 = bflo(w2.x); h1 = bfhi(w2.x); h2 = bflo(w2.y); h3 = bfhi(w2.y);
    a0.x += h0 - u2 * h0;  a1.x += u2 * h0;
    a0.y += h1 - u2 * h1;  a1.y += u2 * h1;
    a0.z += h2 - u2 * h2;  a1.z += u2 * h2;
    a0.w += h3 - u2 * h3;  a1.w += u2 * h3;
    h0 = bflo(w3.x); h1 = bfhi(w3.x); h2 = bflo(w3.y); h3 = bfhi(w3.y);
    a0.x += h0 - u3 * h0;  a1.x += u3 * h0;
    a0.y += h1 - u3 * h1;  a1.y += u3 * h1;
    a0.z += h2 - u3 * h2;  a1.z += u3 * h2;
    a0.w += h3 - u3 * h3;  a1.w += u3 * h3;
  }
  for (; i < end; ++i) {
    unsigned se = sedge[i];
    int s = se & 131071u;
    float u = (float)(se >> 17) * (1.0f / 32767.0f);
    uint2 w = *(const uint2*)(Hb + (size_t)s * 8 + c * 2);
    float h0 = bflo(w.x), h1 = bfhi(w.x), h2 = bflo(w.y), h3 = bfhi(w.y);
    a0.x += h0 - u * h0;  a1.x += u * h0;
    a0.y += h1 - u * h1;  a1.y += u * h1;
    a0.z += h2 - u * h2;  a1.z += u * h2;
    a0.w += h3 - u * h3;  a1.w += u * h3;
  }
  *(float4*)(A0 + (size_t)n * HID + c * 4) = a0;
  *(float4*)(A1 + (size_t)n * HID + c * 4) = a1;
}

// K5: out = log_softmax( (A0@W2[0] + A1@W2[1])/max(deg,1) + H@root2 + bias2 )
__global__ __launch_bounds__(256) void k_final(const float* __restrict__ A0,
    const float* __restrict__ A1, const unsigned* __restrict__ Hb,
    const int* __restrict__ off, const float* __restrict__ W2,
    const float* __restrict__ root2, const float* __restrict__ bias2,
    float* __restrict__ out) {
  int t = threadIdx.x;
  int l = t & 63;
  int j = (l < NC) ? l : 0;
  float w0r[HID], w1r[HID], rr[HID];
#pragma unroll
  for (int k = 0; k < HID; ++k) {
    w0r[k] = W2[k * NC + j];
    w1r[k] = W2[HID * NC + k * NC + j];
    rr[k]  = root2[k * NC + j];
  }
  float b2 = bias2[j];
  int wid = (blockIdx.x * 256 + t) >> 6;
  int nwaves = gridDim.x * 4;
  for (int n0 = wid; n0 < NN; n0 += nwaves) {
    int n = __builtin_amdgcn_readfirstlane(n0);
    const float* a0p = A0 + (size_t)n * HID;
    const float* a1p = A1 + (size_t)n * HID;
    const unsigned* hp = Hb + (size_t)n * 8;
    int e1 = off[n];
    int e0 = (n == 0) ? 0 : off[n - 1];
    float ic = 1.0f / fmaxf((float)(e1 - e0), 1.0f);
    float accm = 0.f, accr = 0.f;
#pragma unroll
    for (int k = 0; k < HID; ++k) {
      accm += a0p[k] * w0r[k];
      accm += a1p[k] * w1r[k];
      unsigned hw = hp[k >> 1];
      float hk = (k & 1) ? bfhi(hw) : bflo(hw);
      accr += hk * rr[k];
    }
    float logit = accm * ic + accr + b2;
    float mx = (l < NC) ? logit : -INFINITY;
#pragma unroll
    for (int o = 32; o >= 1; o >>= 1) mx = fmaxf(mx, __shfl_xor(mx, o));
    float p = (l < NC) ? __expf(logit - mx) : 0.f;
    float sm = p;
#pragma unroll
    for (int o = 32; o >= 1; o >>= 1) sm += __shfl_xor(sm, o);
    if (l < NC) out[(size_t)n * NC + l] = logit - mx - __logf(sm);
  }
}

extern "C" void kernel_launch(void* const* d_in, const int* in_sizes, int n_in,
                              void* d_out, int out_size, void* d_ws, size_t ws_size,
                              hipStream_t stream) {
  const float* x     = (const float*)d_in[0];
  const int*   ei    = (const int*)d_in[1];
  const float* ea    = (const float*)d_in[2];
  const float* W1    = (const float*)d_in[3];
  const float* root1 = (const float*)d_in[4];
  const float* bias1 = (const float*)d_in[5];
  const float* W2    = (const float*)d_in[6];
  const float* root2 = (const float*)d_in[7];
  const float* bias2 = (const float*)d_in[8];
  float* out = (float*)d_out;
  char* base = (char*)d_ws;

  // Layout (bytes):
  //   [0,       6.4M)  XD  (u32[NN*16], bf16 X0|D pairs)   -> later A0 (f32[NN*16])
  //   [6.4M,   12.8M)  XR  (f32[NN*16])                    -> later A1 (f32[NN*16])
  //   [12.8M,  16.0M)  Hb  (u32[NN*8],  bf16 H pairs)
  //   [0,      25.6M)  bstream (int2[NE]) during CSR build only (dead before k_gemm1)
  //   [25.6M,  38.4M)  sedge (u32[NE], src|u15<<17)
  //   [38.4M, ...)     off[NN], bcnt, bbase, bcur
  unsigned* XD = (unsigned*)base;
  float*    XR = (float*)(base + 6400000);
  unsigned* Hb = (unsigned*)(base + 12800000);
  float*    A0 = (float*)base;
  float*    A1 = (float*)(base + 6400000);
  int2*     bstream = (int2*)base;
  unsigned* sedge = (unsigned*)(base + 25600000);
  int*      off   = (int*)(base + 38400000);
  int*      bcnt  = off + NN;
  int*      bbase = bcnt + NBUK;
  int*      bcur  = bbase + NBUK + 1;

  hipMemsetAsync(bcnt, 0, NBUK * sizeof(int), stream);

  // CSR build first (bstream aliases node tables)
  k_bcount<<<NBLK_BKT, 256, 0, stream>>>(ei, bcnt);
  k_bscan<<<1, 256, 0, stream>>>(bcnt, bbase, bcur);
  k_bucketize<<<NBLK_BKT, 256, 0, stream>>>(ei, ea, bcur, bstream);
  k_csr<<<NBUK, 512, 0, stream>>>(bstream, bbase, off, sedge);

  // Dense + pulls
  k_gemm1<<<NBLK_G1, 256, 0, stream>>>(x, W1, root1, bias1, XD, XR);
  k_pull1<<<(NN * 4 + 255) / 256, 256, 0, stream>>>(off, sedge, XD, XR, Hb);
  k_pull2<<<(NN * 4 + 255) / 256, 256, 0, stream>>>(off, sedge, Hb, A0, A1);
  k_final<<<1024, 256, 0, stream>>>(A0, A1, Hb, off, W2, root2, bias2, out);
}

// Round 11
// 219.030 us; speedup vs baseline: 5.2768x; 1.0379x over previous
//
#include <hip/hip_runtime.h>
#include <cstddef>

#define NN 100000
#define NE 3200000
#define FIN 128
#define HID 16
#define NC 40
#define NBUK 196                 // ceil(100000 / 512) node-range buckets
#define CHUNK 4096               // edges per block in bucketing passes
#define NBLK_BKT ((NE + CHUNK - 1) / CHUNK)   // 782
#define NWAVE_G1 (NN / 16)       // 6250 waves, 16 nodes each
#define NBLK_G1 ((NWAVE_G1 + 3) / 4)          // 1563

typedef __attribute__((ext_vector_type(8))) short bf16x8;
typedef __attribute__((ext_vector_type(4))) float f32x4;

// ---- bf16 helpers (RNE pack, cheap unpack) ----
__device__ __forceinline__ unsigned bf16rne(float f) {
  unsigned u = __float_as_uint(f);
  return (u + 0x7fffu + ((u >> 16) & 1u)) >> 16;
}
__device__ __forceinline__ unsigned bfpack(float lo, float hi) {
  return bf16rne(lo) | (bf16rne(hi) << 16);
}
__device__ __forceinline__ float bflo(unsigned w) { return __uint_as_float(w << 16); }
__device__ __forceinline__ float bfhi(unsigned w) { return __uint_as_float(w & 0xffff0000u); }

// ---------- K_PRE: fused [gemm1 | bcount] by block range ----------
// Blocks [0, NBLK_G1): MFMA gemm -> XD (bf16 X0|D pairs), XR (f32 root+bias).
// Blocks [NBLK_G1, NBLK_G1+NBLK_BKT): LDS histogram of dst buckets -> bcnt.
__global__ __launch_bounds__(256) void k_pre(const float* __restrict__ x,
    const float* __restrict__ W1, const float* __restrict__ root1,
    const float* __restrict__ bias1,
    unsigned* __restrict__ XD, float* __restrict__ XR,
    const int* __restrict__ ei, int* __restrict__ bcnt) {
  __shared__ int h[NBUK];
  int t = threadIdx.x;
  if (blockIdx.x >= NBLK_G1) {
    // ---- bcount part ----
    for (int i = t; i < NBUK; i += 256) h[i] = 0;
    __syncthreads();
    int base = (blockIdx.x - NBLK_G1) * CHUNK;
#pragma unroll
    for (int i = 0; i < 16; ++i) {
      int e = base + i * 256 + t;
      if (e < NE) atomicAdd(&h[ei[NE + e] >> 9], 1);
    }
    __syncthreads();
    for (int i = t; i < NBUK; i += 256)
      if (h[i]) atomicAdd(&bcnt[i], h[i]);
    return;
  }
  // ---- gemm1 part: one wave = 16 nodes x 48 cols ----
  int l = t & 63;
  int wv = (blockIdx.x * 256 + t) >> 6;
  int nb = wv * 16;
  if (nb >= NN) return;
  int j16 = l & 15, kg = l >> 4;

  bf16x8 bfrag[3][4];
  const float* wsrc0 = W1;
  const float* wsrc1 = W1 + 2048;
  const float* wsrc2 = root1;
#pragma unroll
  for (int kk = 0; kk < 4; ++kk) {
    int krow = kk * 32 + kg * 8;
#pragma unroll
    for (int b = 0; b < 8; ++b) {
      int o = (krow + b) * 16 + j16;
      bfrag[0][kk][b] = (short)bf16rne(wsrc0[o]);
      bfrag[1][kk][b] = (short)bf16rne(wsrc1[o]);
      bfrag[2][kk][b] = (short)bf16rne(wsrc2[o]);
    }
  }

  f32x4 acc0 = {0.f, 0.f, 0.f, 0.f};
  f32x4 acc1 = {0.f, 0.f, 0.f, 0.f};
  f32x4 acc2 = {0.f, 0.f, 0.f, 0.f};
  const float* xrow = x + (size_t)(nb + j16) * FIN + kg * 8;
#pragma unroll
  for (int kk = 0; kk < 4; ++kk) {
    float4 xa = *(const float4*)(xrow + kk * 32);
    float4 xb = *(const float4*)(xrow + kk * 32 + 4);
    bf16x8 a;
    a[0] = (short)bf16rne(xa.x); a[1] = (short)bf16rne(xa.y);
    a[2] = (short)bf16rne(xa.z); a[3] = (short)bf16rne(xa.w);
    a[4] = (short)bf16rne(xb.x); a[5] = (short)bf16rne(xb.y);
    a[6] = (short)bf16rne(xb.z); a[7] = (short)bf16rne(xb.w);
    acc0 = __builtin_amdgcn_mfma_f32_16x16x32_bf16(a, bfrag[0][kk], acc0, 0, 0, 0);
    acc1 = __builtin_amdgcn_mfma_f32_16x16x32_bf16(a, bfrag[1][kk], acc1, 0, 0, 0);
    acc2 = __builtin_amdgcn_mfma_f32_16x16x32_bf16(a, bfrag[2][kk], acc2, 0, 0, 0);
  }

  float bb = bias1[j16];
#pragma unroll
  for (int r = 0; r < 4; ++r) {
    int n = nb + kg * 4 + r;
    size_t idx = (size_t)n * HID + j16;
    XD[idx] = bfpack(acc0[r], acc1[r] - acc0[r]);
    XR[idx] = acc2[r] + bb;
  }
}

__global__ __launch_bounds__(256) void k_bscan(const int* __restrict__ bcnt,
    int* __restrict__ bbase, int* __restrict__ bcur) {
  __shared__ int scn[256];
  int t = threadIdx.x;
  int v = (t < NBUK) ? bcnt[t] : 0;
  scn[t] = v;
  __syncthreads();
  for (int st = 1; st < 256; st <<= 1) {
    int tmp = (t >= st) ? scn[t - st] : 0;
    __syncthreads();
    scn[t] += tmp;
    __syncthreads();
  }
  if (t < NBUK) { int ex = scn[t] - v; bbase[t] = ex; bcur[t] = ex; }
  if (t == NBUK - 1) bbase[NBUK] = scn[t];
}

// Bucketize: bx = (dst&511)<<17 | src ; bu = u quantized to 8 bits
__global__ __launch_bounds__(256) void k_bucketize(const int* __restrict__ ei,
    const float* __restrict__ ea, int* __restrict__ bcur,
    unsigned* __restrict__ bx, unsigned char* __restrict__ bu) {
  __shared__ int lh[NBUK];
  __shared__ int lbase[NBUK];
  __shared__ int gb[NBUK];
  __shared__ int scn[256];
  __shared__ int meta[CHUNK];
  __shared__ unsigned char ubuf[CHUNK];
  __shared__ unsigned char sbkt[CHUNK];
  int t = threadIdx.x;
  for (int i = t; i < NBUK; i += 256) lh[i] = 0;
  __syncthreads();
  int base = blockIdx.x * CHUNK;
  int rk[16], bk[16], mt[16];
  unsigned char uv[16];
#pragma unroll
  for (int i = 0; i < 16; ++i) {
    int e = base + i * 256 + t;
    if (e < NE) {
      int d = ei[NE + e], sv = ei[e];
      int b = d >> 9;
      rk[i] = atomicAdd(&lh[b], 1);
      bk[i] = b;
      mt[i] = ((d & 511) << 17) | sv;
      uv[i] = (unsigned char)__float2int_rn(ea[e] * 255.0f);
    } else bk[i] = -1;
  }
  __syncthreads();
  int v = (t < NBUK) ? lh[t] : 0;
  scn[t] = v;
  __syncthreads();
  for (int st = 1; st < 256; st <<= 1) {
    int tmp = (t >= st) ? scn[t - st] : 0;
    __syncthreads();
    scn[t] += tmp;
    __syncthreads();
  }
  if (t < NBUK) lbase[t] = scn[t] - v;
  int total = scn[255];
  __syncthreads();
  if (t < NBUK && lh[t] > 0) gb[t] = atomicAdd(&bcur[t], lh[t]);
  __syncthreads();
#pragma unroll
  for (int i = 0; i < 16; ++i) {
    if (bk[i] >= 0) {
      int p = lbase[bk[i]] + rk[i];
      meta[p] = mt[i];
      ubuf[p] = uv[i];
      sbkt[p] = (unsigned char)bk[i];
    }
  }
  __syncthreads();
  for (int s = t; s < total; s += 256) {
    int b = sbkt[s];
    int pos = gb[b] + (s - lbase[b]);
    bx[pos] = (unsigned)meta[s];
    bu[pos] = ubuf[s];
  }
}

// CSR: one block per bucket -> off[] (inclusive row-end) + sedge (src | u8<<17)
__global__ __launch_bounds__(512) void k_csr(const unsigned* __restrict__ bx,
    const unsigned char* __restrict__ bu, const int* __restrict__ bbase,
    int* __restrict__ off, unsigned* __restrict__ sedge) {
  __shared__ int cnt[512];
  __shared__ int scn[512];
  __shared__ int cur[512];
  int b = blockIdx.x, t = threadIdx.x;
  int s0 = bbase[b], s1 = bbase[b + 1];
  cnt[t] = 0;
  __syncthreads();
  for (int i = s0 + t; i < s1; i += 512)
    atomicAdd(&cnt[bx[i] >> 17], 1);
  __syncthreads();
  int v = cnt[t];
  scn[t] = v;
  __syncthreads();
  for (int st = 1; st < 512; st <<= 1) {
    int tmp = (t >= st) ? scn[t - st] : 0;
    __syncthreads();
    scn[t] += tmp;
    __syncthreads();
  }
  int n = (b << 9) + t;
  if (n < NN) off[n] = s0 + scn[t];
  cur[t] = s0 + scn[t] - v;
  __syncthreads();
  for (int i = s0 + t; i < s1; i += 512) {
    unsigned r = bx[i];
    int local = r >> 17;
    int pos = atomicAdd(&cur[local], 1);
    sedge[pos] = (r & 131071u) | ((unsigned)bu[i] << 17);
  }
}

// ---------- pull kernels ----------

// Pull pass 1:  Hb[n] = bf16(elu(mean_e(X0[s]+u*D[s]) + XR[n]))
__global__ __launch_bounds__(256) void k_pull1(const int* __restrict__ off,
    const unsigned* __restrict__ sedge, const unsigned* __restrict__ XD,
    const float* __restrict__ XR, unsigned* __restrict__ Hb) {
  int tid = blockIdx.x * 256 + threadIdx.x;
  int n = tid >> 2, c = tid & 3;
  if (n >= NN) return;
  int start = (n == 0) ? 0 : off[n - 1];
  int end = off[n];
  float4 acc = make_float4(0.f, 0.f, 0.f, 0.f);
  int i = start;
  for (; i + 4 <= end; i += 4) {
    unsigned se0 = sedge[i], se1 = sedge[i + 1];
    unsigned se2 = sedge[i + 2], se3 = sedge[i + 3];
    uint4 w0 = *(const uint4*)(XD + (size_t)(se0 & 131071u) * HID + c * 4);
    uint4 w1 = *(const uint4*)(XD + (size_t)(se1 & 131071u) * HID + c * 4);
    uint4 w2 = *(const uint4*)(XD + (size_t)(se2 & 131071u) * HID + c * 4);
    uint4 w3 = *(const uint4*)(XD + (size_t)(se3 & 131071u) * HID + c * 4);
    float u0 = (float)((se0 >> 17) & 255u) * (1.0f / 255.0f);
    float u1 = (float)((se1 >> 17) & 255u) * (1.0f / 255.0f);
    float u2 = (float)((se2 >> 17) & 255u) * (1.0f / 255.0f);
    float u3 = (float)((se3 >> 17) & 255u) * (1.0f / 255.0f);
    acc.x += bflo(w0.x) + u0 * bfhi(w0.x);
    acc.y += bflo(w0.y) + u0 * bfhi(w0.y);
    acc.z += bflo(w0.z) + u0 * bfhi(w0.z);
    acc.w += bflo(w0.w) + u0 * bfhi(w0.w);
    acc.x += bflo(w1.x) + u1 * bfhi(w1.x);
    acc.y += bflo(w1.y) + u1 * bfhi(w1.y);
    acc.z += bflo(w1.z) + u1 * bfhi(w1.z);
    acc.w += bflo(w1.w) + u1 * bfhi(w1.w);
    acc.x += bflo(w2.x) + u2 * bfhi(w2.x);
    acc.y += bflo(w2.y) + u2 * bfhi(w2.y);
    acc.z += bflo(w2.z) + u2 * bfhi(w2.z);
    acc.w += bflo(w2.w) + u2 * bfhi(w2.w);
    acc.x += bflo(w3.x) + u3 * bfhi(w3.x);
    acc.y += bflo(w3.y) + u3 * bfhi(w3.y);
    acc.z += bflo(w3.z) + u3 * bfhi(w3.z);
    acc.w += bflo(w3.w) + u3 * bfhi(w3.w);
  }
  for (; i < end; ++i) {
    unsigned se = sedge[i];
    int s = se & 131071u;
    float u = (float)((se >> 17) & 255u) * (1.0f / 255.0f);
    uint4 w = *(const uint4*)(XD + (size_t)s * HID + c * 4);
    acc.x += bflo(w.x) + u * bfhi(w.x);
    acc.y += bflo(w.y) + u * bfhi(w.y);
    acc.z += bflo(w.z) + u * bfhi(w.z);
    acc.w += bflo(w.w) + u * bfhi(w.w);
  }
  float ic = 1.0f / fmaxf((float)(end - start), 1.0f);
  float4 r = *(const float4*)(XR + (size_t)n * HID + c * 4);
  float4 h;
  h.x = acc.x * ic + r.x;
  h.y = acc.y * ic + r.y;
  h.z = acc.z * ic + r.z;
  h.w = acc.w * ic + r.w;
  h.x = h.x > 0.f ? h.x : expm1f(h.x);
  h.y = h.y > 0.f ? h.y : expm1f(h.y);
  h.z = h.z > 0.f ? h.z : expm1f(h.z);
  h.w = h.w > 0.f ? h.w : expm1f(h.w);
  uint2 hw;
  hw.x = bfpack(h.x, h.y);
  hw.y = bfpack(h.z, h.w);
  *(uint2*)(Hb + (size_t)n * 8 + c * 2) = hw;
}

// Fused pull2 + final: block = 64 nodes. Phase 1: accumulate A0/A1 into
// registers -> LDS. Phase 2: W2 matvec + log_softmax, write out directly.
__global__ __launch_bounds__(256) void k_pull2f(const int* __restrict__ off,
    const unsigned* __restrict__ sedge, const unsigned* __restrict__ Hb,
    const float* __restrict__ W2, const float* __restrict__ root2,
    const float* __restrict__ bias2, float* __restrict__ out) {
  __shared__ float a0s[64 * 16];
  __shared__ float a1s[64 * 16];
  __shared__ float ics[64];
  int t = threadIdx.x;
  int nb = blockIdx.x * 64;
  int ln0 = t >> 2, c = t & 3;
  int n = nb + ln0;
  float4 a0 = make_float4(0.f, 0.f, 0.f, 0.f);
  float4 a1 = make_float4(0.f, 0.f, 0.f, 0.f);
  int start = 0, end = 0;
  if (n < NN) {
    start = (n == 0) ? 0 : off[n - 1];
    end = off[n];
    int i = start;
    for (; i + 4 <= end; i += 4) {
      unsigned se0 = sedge[i], se1 = sedge[i + 1];
      unsigned se2 = sedge[i + 2], se3 = sedge[i + 3];
      uint2 w0 = *(const uint2*)(Hb + (size_t)(se0 & 131071u) * 8 + c * 2);
      uint2 w1 = *(const uint2*)(Hb + (size_t)(se1 & 131071u) * 8 + c * 2);
      uint2 w2 = *(const uint2*)(Hb + (size_t)(se2 & 131071u) * 8 + c * 2);
      uint2 w3 = *(const uint2*)(Hb + (size_t)(se3 & 131071u) * 8 + c * 2);
      float u0 = (float)((se0 >> 17) & 255u) * (1.0f / 255.0f);
      float u1 = (float)((se1 >> 17) & 255u) * (1.0f / 255.0f);
      float u2 = (float)((se2 >> 17) & 255u) * (1.0f / 255.0f);
      float u3 = (float)((se3 >> 17) & 255u) * (1.0f / 255.0f);
      float h0, h1, h2, h3;
      h0 = bflo(w0.x); h1 = bfhi(w0.x); h2 = bflo(w0.y); h3 = bfhi(w0.y);
      a0.x += h0 - u0 * h0;  a1.x += u0 * h0;
      a0.y += h1 - u0 * h1;  a1.y += u0 * h1;
      a0.z += h2 - u0 * h2;  a1.z += u0 * h2;
      a0.w += h3 - u0 * h3;  a1.w += u0 * h3;
      h0 = bflo(w1.x); h1 = bfhi(w1.x); h2 = bflo(w1.y); h3 = bfhi(w1.y);
      a0.x += h0 - u1 * h0;  a1.x += u1 * h0;
      a0.y += h1 - u1 * h1;  a1.y += u1 * h1;
      a0.z += h2 - u1 * h2;  a1.z += u1 * h2;
      a0.w += h3 - u1 * h3;  a1.w += u1 * h3;
      h0 = bflo(w2.x); h1 = bfhi(w2.x); h2 = bflo(w2.y); h3 = bfhi(w2.y);
      a0.x += h0 - u2 * h0;  a1.x += u2 * h0;
      a0.y += h1 - u2 * h1;  a1.y += u2 * h1;
      a0.z += h2 - u2 * h2;  a1.z += u2 * h2;
      a0.w += h3 - u2 * h3;  a1.w += u2 * h3;
      h0 = bflo(w3.x); h1 = bfhi(w3.x); h2 = bflo(w3.y); h3 = bfhi(w3.y);
      a0.x += h0 - u3 * h0;  a1.x += u3 * h0;
      a0.y += h1 - u3 * h1;  a1.y += u3 * h1;
      a0.z += h2 - u3 * h2;  a1.z += u3 * h2;
      a0.w += h3 - u3 * h3;  a1.w += u3 * h3;
    }
    for (; i < end; ++i) {
      unsigned se = sedge[i];
      int s = se & 131071u;
      float u = (float)((se >> 17) & 255u) * (1.0f / 255.0f);
      uint2 w = *(const uint2*)(Hb + (size_t)s * 8 + c * 2);
      float h0 = bflo(w.x), h1 = bfhi(w.x), h2 = bflo(w.y), h3 = bfhi(w.y);
      a0.x += h0 - u * h0;  a1.x += u * h0;
      a0.y += h1 - u * h1;  a1.y += u * h1;
      a0.z += h2 - u * h2;  a1.z += u * h2;
      a0.w += h3 - u * h3;  a1.w += u * h3;
    }
  }
  *(float4*)&a0s[ln0 * 16 + c * 4] = a0;
  *(float4*)&a1s[ln0 * 16 + c * 4] = a1;
  if (c == 0) ics[ln0] = 1.0f / fmaxf((float)(end - start), 1.0f);
  __syncthreads();

  // Phase 2: lane l owns column j; weights in registers; node data from LDS.
  int l = t & 63;
  int wv = t >> 6;                      // wave id 0..3
  int j = (l < NC) ? l : 0;
  float w0r[HID], w1r[HID], rr[HID];
#pragma unroll
  for (int k = 0; k < HID; ++k) {
    w0r[k] = W2[k * NC + j];
    w1r[k] = W2[HID * NC + k * NC + j];
    rr[k]  = root2[k * NC + j];
  }
  float b2 = bias2[j];
#pragma unroll 1
  for (int q = 0; q < 16; ++q) {
    int ln = wv * 16 + q;
    int nn = nb + ln;
    if (nn >= NN) break;
    nn = __builtin_amdgcn_readfirstlane(nn);
    float ic = ics[ln];
    const unsigned* hp = Hb + (size_t)nn * 8;
    float accm = 0.f, accr = 0.f;
#pragma unroll
    for (int k = 0; k < HID; ++k) {
      accm += a0s[ln * 16 + k] * w0r[k];
      accm += a1s[ln * 16 + k] * w1r[k];
      unsigned hw = hp[k >> 1];
      float hk = (k & 1) ? bfhi(hw) : bflo(hw);
      accr += hk * rr[k];
    }
    float logit = accm * ic + accr + b2;
    float mx = (l < NC) ? logit : -INFINITY;
#pragma unroll
    for (int o = 32; o >= 1; o >>= 1) mx = fmaxf(mx, __shfl_xor(mx, o));
    float p = (l < NC) ? __expf(logit - mx) : 0.f;
    float sm = p;
#pragma unroll
    for (int o = 32; o >= 1; o >>= 1) sm += __shfl_xor(sm, o);
    if (l < NC) out[(size_t)nn * NC + l] = logit - mx - __logf(sm);
  }
}

extern "C" void kernel_launch(void* const* d_in, const int* in_sizes, int n_in,
                              void* d_out, int out_size, void* d_ws, size_t ws_size,
                              hipStream_t stream) {
  const float* x     = (const float*)d_in[0];
  const int*   ei    = (const int*)d_in[1];
  const float* ea    = (const float*)d_in[2];
  const float* W1    = (const float*)d_in[3];
  const float* root1 = (const float*)d_in[4];
  const float* bias1 = (const float*)d_in[5];
  const float* W2    = (const float*)d_in[6];
  const float* root2 = (const float*)d_in[7];
  const float* bias2 = (const float*)d_in[8];
  float* out = (float*)d_out;
  char* base = (char*)d_ws;

  // Layout (bytes) — NO aliasing (gemm overlaps CSR build now):
  //   [0,       6.4M)  XD  (u32[NN*16], bf16 X0|D pairs)
  //   [6.4M,   12.8M)  XR  (f32[NN*16])
  //   [12.8M,  16.0M)  Hb  (u32[NN*8],  bf16 H pairs)
  //   [16.0M,  28.8M)  bx  (u32[NE])
  //   [28.8M,  32.0M)  bu  (u8[NE])
  //   [32.0M,  44.8M)  sedge (u32[NE], src | u8<<17)
  //   [44.8M,  45.2M)  off[NN]
  //   then bcnt[NBUK], bbase[NBUK+1], bcur[NBUK]
  unsigned*      XD    = (unsigned*)base;
  float*         XR    = (float*)(base + 6400000);
  unsigned*      Hb    = (unsigned*)(base + 12800000);
  unsigned*      bx    = (unsigned*)(base + 16000000);
  unsigned char* bu    = (unsigned char*)(base + 28800000);
  unsigned*      sedge = (unsigned*)(base + 32000000);
  int*           off   = (int*)(base + 44800000);
  int*           bcnt  = off + NN;
  int*           bbase = bcnt + NBUK;
  int*           bcur  = bbase + NBUK + 1;

  hipMemsetAsync(bcnt, 0, NBUK * sizeof(int), stream);

  k_pre<<<NBLK_G1 + NBLK_BKT, 256, 0, stream>>>(x, W1, root1, bias1, XD, XR, ei, bcnt);
  k_bscan<<<1, 256, 0, stream>>>(bcnt, bbase, bcur);
  k_bucketize<<<NBLK_BKT, 256, 0, stream>>>(ei, ea, bcur, bx, bu);
  k_csr<<<NBUK, 512, 0, stream>>>(bx, bu, bbase, off, sedge);
  k_pull1<<<(NN * 4 + 255) / 256, 256, 0, stream>>>(off, sedge, XD, XR, Hb);
  k_pull2f<<<(NN + 63) / 64, 256, 0, stream>>>(off, sedge, Hb, W2, root2, bias2, out);
}

// Round 13
// 205.948 us; speedup vs baseline: 5.6119x; 1.0635x over previous
//
#include <hip/hip_runtime.h>
#include <cstddef>

#define NN 100000
#define NE 3200000
#define FIN 128
#define HID 16
#define NC 40
#define NBUK 196                 // ceil(100000 / 512) node-range buckets
#define CHUNK 4096               // edges per block in bucketing passes
#define NBLK_BKT ((NE + CHUNK - 1) / CHUNK)   // 782
#define NWAVE_G1 (NN / 16)       // 6250 waves, 16 nodes each
#define NBLK_G1 ((NWAVE_G1 + 3) / 4)          // 1563

typedef __attribute__((ext_vector_type(8))) short bf16x8;
typedef __attribute__((ext_vector_type(4))) float f32x4;
typedef __attribute__((ext_vector_type(2))) float f32x2;

// ---- bf16 helpers (RNE pack, cheap unpack) ----
__device__ __forceinline__ unsigned bf16rne(float f) {
  unsigned u = __float_as_uint(f);
  return (u + 0x7fffu + ((u >> 16) & 1u)) >> 16;
}
__device__ __forceinline__ unsigned bfpack(float lo, float hi) {
  return bf16rne(lo) | (bf16rne(hi) << 16);
}
__device__ __forceinline__ float bflo(unsigned w) { return __uint_as_float(w << 16); }
__device__ __forceinline__ float bfhi(unsigned w) { return __uint_as_float(w & 0xffff0000u); }

// ---- fp8 e4m3 helpers ----
__device__ __forceinline__ unsigned short fp8pack2(float a, float b) {
#if __has_builtin(__builtin_amdgcn_cvt_pk_fp8_f32)
  return (unsigned short)__builtin_amdgcn_cvt_pk_fp8_f32(a, b, 0, false);
#else
  // y-domain bit trick: e4m3 (E,M) <-> f32 with exp field E, top-3 mant M
  auto enc1 = [](float f) -> unsigned {
    float y = f * 0x1p-120f;
    unsigned bb = __float_as_uint(y);
    unsigned s = (bb >> 24) & 0x80u;
    unsigned m = bb & 0x7fffffffu;
    const unsigned maxb = (15u << 23) | (6u << 20);   // 448
    m = m + 0x7ffffu + ((m >> 20) & 1u);              // RNE at bit 20
    if (m > maxb) m = maxb;
    return s | (m >> 20);
  };
  return (unsigned short)(enc1(a) | (enc1(b) << 8));
#endif
}
template <bool HI>
__device__ __forceinline__ f32x2 fp8unpack2(unsigned w) {
#if __has_builtin(__builtin_amdgcn_cvt_pk_f32_fp8)
  return __builtin_amdgcn_cvt_pk_f32_fp8((int)w, HI);
#else
  unsigned w2 = HI ? (w >> 16) : w;
  auto dec1 = [](unsigned b) -> float {
    unsigned f = ((b & 0x80u) << 24) | ((b & 0x7fu) << 20);
    return __uint_as_float(f) * 0x1p120f;
  };
  f32x2 r;
  r.x = dec1(w2 & 0xffu);
  r.y = dec1((w2 >> 8) & 0xffu);
  return r;
#endif
}

// ---------- K_PRE: fused [gemm1 | bcount] by block range ----------
// Blocks [0, NBLK_G1): MFMA gemm -> XD8 (fp8 X0|D interleaved, 32B/node),
//                      XR (f32 root+bias).
// Blocks [NBLK_G1, ...): LDS histogram of dst buckets -> bcnt.
__global__ __launch_bounds__(256) void k_pre(const float* __restrict__ x,
    const float* __restrict__ W1, const float* __restrict__ root1,
    const float* __restrict__ bias1,
    unsigned char* __restrict__ XD8, float* __restrict__ XR,
    const int* __restrict__ ei, int* __restrict__ bcnt) {
  __shared__ int h[NBUK];
  int t = threadIdx.x;
  if (blockIdx.x >= NBLK_G1) {
    for (int i = t; i < NBUK; i += 256) h[i] = 0;
    __syncthreads();
    int base = (blockIdx.x - NBLK_G1) * CHUNK;
#pragma unroll
    for (int i = 0; i < 16; ++i) {
      int e = base + i * 256 + t;
      if (e < NE) atomicAdd(&h[ei[NE + e] >> 9], 1);
    }
    __syncthreads();
    for (int i = t; i < NBUK; i += 256)
      if (h[i]) atomicAdd(&bcnt[i], h[i]);
    return;
  }
  int l = t & 63;
  int wv = (blockIdx.x * 256 + t) >> 6;
  int nb = wv * 16;
  if (nb >= NN) return;
  int j16 = l & 15, kg = l >> 4;

  bf16x8 bfrag[3][4];
  const float* wsrc0 = W1;
  const float* wsrc1 = W1 + 2048;
  const float* wsrc2 = root1;
#pragma unroll
  for (int kk = 0; kk < 4; ++kk) {
    int krow = kk * 32 + kg * 8;
#pragma unroll
    for (int b = 0; b < 8; ++b) {
      int o = (krow + b) * 16 + j16;
      bfrag[0][kk][b] = (short)bf16rne(wsrc0[o]);
      bfrag[1][kk][b] = (short)bf16rne(wsrc1[o]);
      bfrag[2][kk][b] = (short)bf16rne(wsrc2[o]);
    }
  }

  f32x4 acc0 = {0.f, 0.f, 0.f, 0.f};
  f32x4 acc1 = {0.f, 0.f, 0.f, 0.f};
  f32x4 acc2 = {0.f, 0.f, 0.f, 0.f};
  const float* xrow = x + (size_t)(nb + j16) * FIN + kg * 8;
#pragma unroll
  for (int kk = 0; kk < 4; ++kk) {
    float4 xa = *(const float4*)(xrow + kk * 32);
    float4 xb = *(const float4*)(xrow + kk * 32 + 4);
    bf16x8 a;
    a[0] = (short)bf16rne(xa.x); a[1] = (short)bf16rne(xa.y);
    a[2] = (short)bf16rne(xa.z); a[3] = (short)bf16rne(xa.w);
    a[4] = (short)bf16rne(xb.x); a[5] = (short)bf16rne(xb.y);
    a[6] = (short)bf16rne(xb.z); a[7] = (short)bf16rne(xb.w);
    acc0 = __builtin_amdgcn_mfma_f32_16x16x32_bf16(a, bfrag[0][kk], acc0, 0, 0, 0);
    acc1 = __builtin_amdgcn_mfma_f32_16x16x32_bf16(a, bfrag[1][kk], acc1, 0, 0, 0);
    acc2 = __builtin_amdgcn_mfma_f32_16x16x32_bf16(a, bfrag[2][kk], acc2, 0, 0, 0);
  }

  float bb = bias1[j16];
#pragma unroll
  for (int r = 0; r < 4; ++r) {
    int n = nb + kg * 4 + r;
    *(unsigned short*)(XD8 + (size_t)n * 32 + j16 * 2) =
        fp8pack2(acc0[r], acc1[r] - acc0[r]);
    XR[(size_t)n * HID + j16] = acc2[r] + bb;
  }
}

__global__ __launch_bounds__(256) void k_bscan(const int* __restrict__ bcnt,
    int* __restrict__ bbase, int* __restrict__ bcur) {
  __shared__ int scn[256];
  int t = threadIdx.x;
  int v = (t < NBUK) ? bcnt[t] : 0;
  scn[t] = v;
  __syncthreads();
  for (int st = 1; st < 256; st <<= 1) {
    int tmp = (t >= st) ? scn[t - st] : 0;
    __syncthreads();
    scn[t] += tmp;
    __syncthreads();
  }
  if (t < NBUK) { int ex = scn[t] - v; bbase[t] = ex; bcur[t] = ex; }
  if (t == NBUK - 1) bbase[NBUK] = scn[t];
}

// Bucketize: bx = (dst&511)<<17 | src ; bu = u quantized to 8 bits
__global__ __launch_bounds__(256) void k_bucketize(const int* __restrict__ ei,
    const float* __restrict__ ea, int* __restrict__ bcur,
    unsigned* __restrict__ bx, unsigned char* __restrict__ bu) {
  __shared__ int lh[NBUK];
  __shared__ int lbase[NBUK];
  __shared__ int gb[NBUK];
  __shared__ int scn[256];
  __shared__ int meta[CHUNK];
  __shared__ unsigned char ubuf[CHUNK];
  __shared__ unsigned char sbkt[CHUNK];
  int t = threadIdx.x;
  for (int i = t; i < NBUK; i += 256) lh[i] = 0;
  __syncthreads();
  int base = blockIdx.x * CHUNK;
  int rk[16], bk[16], mt[16];
  unsigned char uv[16];
#pragma unroll
  for (int i = 0; i < 16; ++i) {
    int e = base + i * 256 + t;
    if (e < NE) {
      int d = ei[NE + e], sv = ei[e];
      int b = d >> 9;
      rk[i] = atomicAdd(&lh[b], 1);
      bk[i] = b;
      mt[i] = ((d & 511) << 17) | sv;
      uv[i] = (unsigned char)__float2int_rn(ea[e] * 255.0f);
    } else bk[i] = -1;
  }
  __syncthreads();
  int v = (t < NBUK) ? lh[t] : 0;
  scn[t] = v;
  __syncthreads();
  for (int st = 1; st < 256; st <<= 1) {
    int tmp = (t >= st) ? scn[t - st] : 0;
    __syncthreads();
    scn[t] += tmp;
    __syncthreads();
  }
  if (t < NBUK) lbase[t] = scn[t] - v;
  int total = scn[255];
  __syncthreads();
  if (t < NBUK && lh[t] > 0) gb[t] = atomicAdd(&bcur[t], lh[t]);
  __syncthreads();
#pragma unroll
  for (int i = 0; i < 16; ++i) {
    if (bk[i] >= 0) {
      int p = lbase[bk[i]] + rk[i];
      meta[p] = mt[i];
      ubuf[p] = uv[i];
      sbkt[p] = (unsigned char)bk[i];
    }
  }
  __syncthreads();
  for (int s = t; s < total; s += 256) {
    int b = sbkt[s];
    int pos = gb[b] + (s - lbase[b]);
    bx[pos] = (unsigned)meta[s];
    bu[pos] = ubuf[s];
  }
}

// CSR: one block per bucket -> off[] (inclusive row-end) + sedge (src | u8<<17)
__global__ __launch_bounds__(512) void k_csr(const unsigned* __restrict__ bx,
    const unsigned char* __restrict__ bu, const int* __restrict__ bbase,
    int* __restrict__ off, unsigned* __restrict__ sedge) {
  __shared__ int cnt[512];
  __shared__ int scn[512];
  __shared__ int cur[512];
  int b = blockIdx.x, t = threadIdx.x;
  int s0 = bbase[b], s1 = bbase[b + 1];
  cnt[t] = 0;
  __syncthreads();
  for (int i = s0 + t; i < s1; i += 512)
    atomicAdd(&cnt[bx[i] >> 17], 1);
  __syncthreads();
  int v = cnt[t];
  scn[t] = v;
  __syncthreads();
  for (int st = 1; st < 512; st <<= 1) {
    int tmp = (t >= st) ? scn[t - st] : 0;
    __syncthreads();
    scn[t] += tmp;
    __syncthreads();
  }
  int n = (b << 9) + t;
  if (n < NN) off[n] = s0 + scn[t];
  cur[t] = s0 + scn[t] - v;
  __syncthreads();
  for (int i = s0 + t; i < s1; i += 512) {
    unsigned r = bx[i];
    int local = r >> 17;
    int pos = atomicAdd(&cur[local], 1);
    sedge[pos] = (r & 131071u) | ((unsigned)bu[i] << 17);
  }
}

// ---------- pull kernels ----------

// Pull pass 1:  Hb[n] = bf16(elu(mean_e(X0[s]+u*D[s]) + XR[n]))
// XD8 gathers: 8B/thread from the 3.2 MB fp8 table (L2-resident).
__global__ __launch_bounds__(256) void k_pull1(const int* __restrict__ off,
    const unsigned* __restrict__ sedge, const unsigned char* __restrict__ XD8,
    const float* __restrict__ XR, unsigned* __restrict__ Hb) {
  int tid = blockIdx.x * 256 + threadIdx.x;
  int n = tid >> 2, c = tid & 3;
  if (n >= NN) return;
  int start = (n == 0) ? 0 : off[n - 1];
  int end = off[n];
  float4 acc = make_float4(0.f, 0.f, 0.f, 0.f);
  int i = start;
  for (; i + 4 <= end; i += 4) {
    unsigned se0 = sedge[i], se1 = sedge[i + 1];
    unsigned se2 = sedge[i + 2], se3 = sedge[i + 3];
    uint2 w0 = *(const uint2*)(XD8 + (size_t)(se0 & 131071u) * 32 + c * 8);
    uint2 w1 = *(const uint2*)(XD8 + (size_t)(se1 & 131071u) * 32 + c * 8);
    uint2 w2 = *(const uint2*)(XD8 + (size_t)(se2 & 131071u) * 32 + c * 8);
    uint2 w3 = *(const uint2*)(XD8 + (size_t)(se3 & 131071u) * 32 + c * 8);
    float u0 = (float)((se0 >> 17) & 255u) * (1.0f / 255.0f);
    float u1 = (float)((se1 >> 17) & 255u) * (1.0f / 255.0f);
    float u2 = (float)((se2 >> 17) & 255u) * (1.0f / 255.0f);
    float u3 = (float)((se3 >> 17) & 255u) * (1.0f / 255.0f);
    f32x2 p;
    p = fp8unpack2<false>(w0.x); acc.x += p.x + u0 * p.y;
    p = fp8unpack2<true>(w0.x);  acc.y += p.x + u0 * p.y;
    p = fp8unpack2<false>(w0.y); acc.z += p.x + u0 * p.y;
    p = fp8unpack2<true>(w0.y);  acc.w += p.x + u0 * p.y;
    p = fp8unpack2<false>(w1.x); acc.x += p.x + u1 * p.y;
    p = fp8unpack2<true>(w1.x);  acc.y += p.x + u1 * p.y;
    p = fp8unpack2<false>(w1.y); acc.z += p.x + u1 * p.y;
    p = fp8unpack2<true>(w1.y);  acc.w += p.x + u1 * p.y;
    p = fp8unpack2<false>(w2.x); acc.x += p.x + u2 * p.y;
    p = fp8unpack2<true>(w2.x);  acc.y += p.x + u2 * p.y;
    p = fp8unpack2<false>(w2.y); acc.z += p.x + u2 * p.y;
    p = fp8unpack2<true>(w2.y);  acc.w += p.x + u2 * p.y;
    p = fp8unpack2<false>(w3.x); acc.x += p.x + u3 * p.y;
    p = fp8unpack2<true>(w3.x);  acc.y += p.x + u3 * p.y;
    p = fp8unpack2<false>(w3.y); acc.z += p.x + u3 * p.y;
    p = fp8unpack2<true>(w3.y);  acc.w += p.x + u3 * p.y;
  }
  for (; i < end; ++i) {
    unsigned se = sedge[i];
    int s = se & 131071u;
    float u = (float)((se >> 17) & 255u) * (1.0f / 255.0f);
    uint2 w = *(const uint2*)(XD8 + (size_t)s * 32 + c * 8);
    f32x2 p;
    p = fp8unpack2<false>(w.x); acc.x += p.x + u * p.y;
    p = fp8unpack2<true>(w.x);  acc.y += p.x + u * p.y;
    p = fp8unpack2<false>(w.y); acc.z += p.x + u * p.y;
    p = fp8unpack2<true>(w.y);  acc.w += p.x + u * p.y;
  }
  float ic = 1.0f / fmaxf((float)(end - start), 1.0f);
  float4 r = *(const float4*)(XR + (size_t)n * HID + c * 4);
  float4 h;
  h.x = acc.x * ic + r.x;
  h.y = acc.y * ic + r.y;
  h.z = acc.z * ic + r.z;
  h.w = acc.w * ic + r.w;
  h.x = h.x > 0.f ? h.x : expm1f(h.x);
  h.y = h.y > 0.f ? h.y : expm1f(h.y);
  h.z = h.z > 0.f ? h.z : expm1f(h.z);
  h.w = h.w > 0.f ? h.w : expm1f(h.w);
  uint2 hw;
  hw.x = bfpack(h.x, h.y);
  hw.y = bfpack(h.z, h.w);
  *(uint2*)(Hb + (size_t)n * 8 + c * 2) = hw;
}

// Fused pull2 + final: block = 64 nodes. Phase 1: accumulate A0/A1 into
// registers -> LDS. Phase 2: W2 matvec + log_softmax, write out directly.
__global__ __launch_bounds__(256) void k_pull2f(const int* __restrict__ off,
    const unsigned* __restrict__ sedge, const unsigned* __restrict__ Hb,
    const float* __restrict__ W2, const float* __restrict__ root2,
    const float* __restrict__ bias2, float* __restrict__ out) {
  __shared__ float a0s[64 * 16];
  __shared__ float a1s[64 * 16];
  __shared__ float ics[64];
  int t = threadIdx.x;
  int nb = blockIdx.x * 64;
  int ln0 = t >> 2, c = t & 3;
  int n = nb + ln0;
  float4 a0 = make_float4(0.f, 0.f, 0.f, 0.f);
  float4 a1 = make_float4(0.f, 0.f, 0.f, 0.f);
  int start = 0, end = 0;
  if (n < NN) {
    start = (n == 0) ? 0 : off[n - 1];
    end = off[n];
    int i = start;
    for (; i + 4 <= end; i += 4) {
      unsigned se0 = sedge[i], se1 = sedge[i + 1];
      unsigned se2 = sedge[i + 2], se3 = sedge[i + 3];
      uint2 w0 = *(const uint2*)(Hb + (size_t)(se0 & 131071u) * 8 + c * 2);
      uint2 w1 = *(const uint2*)(Hb + (size_t)(se1 & 131071u) * 8 + c * 2);
      uint2 w2 = *(const uint2*)(Hb + (size_t)(se2 & 131071u) * 8 + c * 2);
      uint2 w3 = *(const uint2*)(Hb + (size_t)(se3 & 131071u) * 8 + c * 2);
      float u0 = (float)((se0 >> 17) & 255u) * (1.0f / 255.0f);
      float u1 = (float)((se1 >> 17) & 255u) * (1.0f / 255.0f);
      float u2 = (float)((se2 >> 17) & 255u) * (1.0f / 255.0f);
      float u3 = (float)((se3 >> 17) & 255u) * (1.0f / 255.0f);
      float h0, h1, h2, h3;
      h0 = bflo(w0.x); h1 = bfhi(w0.x); h2 = bflo(w0.y); h3 = bfhi(w0.y);
      a0.x += h0 - u0 * h0;  a1.x += u0 * h0;
      a0.y += h1 - u0 * h1;  a1.y += u0 * h1;
      a0.z += h2 - u0 * h2;  a1.z += u0 * h2;
      a0.w += h3 - u0 * h3;  a1.w += u0 * h3;
      h0 = bflo(w1.x); h1 = bfhi(w1.x); h2 = bflo(w1.y); h3 = bfhi(w1.y);
      a0.x += h0 - u1 * h0;  a1.x += u1 * h0;
      a0.y += h1 - u1 * h1;  a1.y += u1 * h1;
      a0.z += h2 - u1 * h2;  a1.z += u1 * h2;
      a0.w += h3 - u1 * h3;  a1.w += u1 * h3;
      h0 = bflo(w2.x); h1 = bfhi(w2.x); h2 = bflo(w2.y); h3 = bfhi(w2.y);
      a0.x += h0 - u2 * h0;  a1.x += u2 * h0;
      a0.y += h1 - u2 * h1;  a1.y += u2 * h1;
      a0.z += h2 - u2 * h2;  a1.z += u2 * h2;
      a0.w += h3 - u2 * h3;  a1.w += u2 * h3;
      h0 = bflo(w3.x); h1 = bfhi(w3.x); h2 = bflo(w3.y); h3 = bfhi(w3.y);
      a0.x += h0 - u3 * h0;  a1.x += u3 * h0;
      a0.y += h1 - u3 * h1;  a1.y += u3 * h1;
      a0.z += h2 - u3 * h2;  a1.z += u3 * h2;
      a0.w += h3 - u3 * h3;  a1.w += u3 * h3;
    }
    for (; i < end; ++i) {
      unsigned se = sedge[i];
      int s = se & 131071u;
      float u = (float)((se >> 17) & 255u) * (1.0f / 255.0f);
      uint2 w = *(const uint2*)(Hb + (size_t)s * 8 + c * 2);
      float h0 = bflo(w.x), h1 = bfhi(w.x), h2 = bflo(w.y), h3 = bfhi(w.y);
      a0.x += h0 - u * h0;  a1.x += u * h0;
      a0.y += h1 - u * h1;  a1.y += u * h1;
      a0.z += h2 - u * h2;  a1.z += u * h2;
      a0.w += h3 - u * h3;  a1.w += u * h3;
    }
  }
  *(float4*)&a0s[ln0 * 16 + c * 4] = a0;
  *(float4*)&a1s[ln0 * 16 + c * 4] = a1;
  if (c == 0) ics[ln0] = 1.0f / fmaxf((float)(end - start), 1.0f);
  __syncthreads();

  // Phase 2: lane l owns column j; weights in registers; node data from LDS.
  int l = t & 63;
  int wv = t >> 6;                      // wave id 0..3
  int j = (l < NC) ? l : 0;
  float w0r[HID], w1r[HID], rr[HID];
#pragma unroll
  for (int k = 0; k < HID; ++k) {
    w0r[k] = W2[k * NC + j];
    w1r[k] = W2[HID * NC + k * NC + j];
    rr[k]  = root2[k * NC + j];
  }
  float b2 = bias2[j];
#pragma unroll 1
  for (int q = 0; q < 16; ++q) {
    int ln = wv * 16 + q;
    int nn = nb + ln;
    if (nn >= NN) break;
    nn = __builtin_amdgcn_readfirstlane(nn);
    float ic = ics[ln];
    const unsigned* hp = Hb + (size_t)nn * 8;
    float accm = 0.f, accr = 0.f;
#pragma unroll
    for (int k = 0; k < HID; ++k) {
      accm += a0s[ln * 16 + k] * w0r[k];
      accm += a1s[ln * 16 + k] * w1r[k];
      unsigned hw = hp[k >> 1];
      float hk = (k & 1) ? bfhi(hw) : bflo(hw);
      accr += hk * rr[k];
    }
    float logit = accm * ic + accr + b2;
    float mx = (l < NC) ? logit : -INFINITY;
#pragma unroll
    for (int o = 32; o >= 1; o >>= 1) mx = fmaxf(mx, __shfl_xor(mx, o));
    float p = (l < NC) ? __expf(logit - mx) : 0.f;
    float sm = p;
#pragma unroll
    for (int o = 32; o >= 1; o >>= 1) sm += __shfl_xor(sm, o);
    if (l < NC) out[(size_t)nn * NC + l] = logit - mx - __logf(sm);
  }
}

extern "C" void kernel_launch(void* const* d_in, const int* in_sizes, int n_in,
                              void* d_out, int out_size, void* d_ws, size_t ws_size,
                              hipStream_t stream) {
  const float* x     = (const float*)d_in[0];
  const int*   ei    = (const int*)d_in[1];
  const float* ea    = (const float*)d_in[2];
  const float* W1    = (const float*)d_in[3];
  const float* root1 = (const float*)d_in[4];
  const float* bias1 = (const float*)d_in[5];
  const float* W2    = (const float*)d_in[6];
  const float* root2 = (const float*)d_in[7];
  const float* bias2 = (const float*)d_in[8];
  float* out = (float*)d_out;
  char* base = (char*)d_ws;

  // Layout (bytes) — NO aliasing:
  //   [0,       3.2M)  XD8 (u8[NN*32], fp8 X0|D interleaved)
  //   [3.2M,    9.6M)  XR  (f32[NN*16])
  //   [9.6M,   12.8M)  Hb  (u32[NN*8],  bf16 H pairs)
  //   [12.8M,  25.6M)  bx  (u32[NE])
  //   [25.6M,  28.8M)  bu  (u8[NE])
  //   [28.8M,  41.6M)  sedge (u32[NE], src | u8<<17)
  //   [41.6M,  42.0M)  off[NN]
  //   then bcnt[NBUK], bbase[NBUK+1], bcur[NBUK]
  unsigned char* XD8   = (unsigned char*)base;
  float*         XR    = (float*)(base + 3200000);
  unsigned*      Hb    = (unsigned*)(base + 9600000);
  unsigned*      bx    = (unsigned*)(base + 12800000);
  unsigned char* bu    = (unsigned char*)(base + 25600000);
  unsigned*      sedge = (unsigned*)(base + 28800000);
  int*           off   = (int*)(base + 41600000);
  int*           bcnt  = off + NN;
  int*           bbase = bcnt + NBUK;
  int*           bcur  = bbase + NBUK + 1;

  (void)hipMemsetAsync(bcnt, 0, NBUK * sizeof(int), stream);

  k_pre<<<NBLK_G1 + NBLK_BKT, 256, 0, stream>>>(x, W1, root1, bias1, XD8, XR, ei, bcnt);
  k_bscan<<<1, 256, 0, stream>>>(bcnt, bbase, bcur);
  k_bucketize<<<NBLK_BKT, 256, 0, stream>>>(ei, ea, bcur, bx, bu);
  k_csr<<<NBUK, 512, 0, stream>>>(bx, bu, bbase, off, sedge);
  k_pull1<<<(NN * 4 + 255) / 256, 256, 0, stream>>>(off, sedge, XD8, XR, Hb);
  k_pull2f<<<(NN + 63) / 64, 256, 0, stream>>>(off, sedge, Hb, W2, root2, bias2, out);
}

// Round 14
// 205.176 us; speedup vs baseline: 5.6330x; 1.0038x over previous
//
#include <hip/hip_runtime.h>
#include <cstddef>

#define NN 100000
#define NE 3200000
#define FIN 128
#define HID 16
#define NC 40
#define NBUK 196                 // ceil(100000 / 512) node-range buckets
#define CHUNK 4096               // edges per block in bucketing passes
#define NBLK_BKT ((NE + CHUNK - 1) / CHUNK)   // 782
#define NWAVE_G1 (NN / 16)       // 6250 waves, 16 nodes each
#define NBLK_G1 ((NWAVE_G1 + 3) / 4)          // 1563

typedef __attribute__((ext_vector_type(8))) short bf16x8;
typedef __attribute__((ext_vector_type(4))) float f32x4;
typedef __attribute__((ext_vector_type(2))) float f32x2;

// ---- bf16 helpers (RNE pack, cheap unpack) ----
__device__ __forceinline__ unsigned bf16rne(float f) {
  unsigned u = __float_as_uint(f);
  return (u + 0x7fffu + ((u >> 16) & 1u)) >> 16;
}
__device__ __forceinline__ unsigned bfpack(float lo, float hi) {
  return bf16rne(lo) | (bf16rne(hi) << 16);
}
__device__ __forceinline__ float bflo(unsigned w) { return __uint_as_float(w << 16); }
__device__ __forceinline__ float bfhi(unsigned w) { return __uint_as_float(w & 0xffff0000u); }

// ---- fp8 e4m3 helpers ----
__device__ __forceinline__ unsigned short fp8pack2(float a, float b) {
#if __has_builtin(__builtin_amdgcn_cvt_pk_fp8_f32)
  return (unsigned short)__builtin_amdgcn_cvt_pk_fp8_f32(a, b, 0, false);
#else
  auto enc1 = [](float f) -> unsigned {
    float y = f * 0x1p-120f;
    unsigned bb = __float_as_uint(y);
    unsigned s = (bb >> 24) & 0x80u;
    unsigned m = bb & 0x7fffffffu;
    const unsigned maxb = (15u << 23) | (6u << 20);   // 448
    m = m + 0x7ffffu + ((m >> 20) & 1u);              // RNE at bit 20
    if (m > maxb) m = maxb;
    return s | (m >> 20);
  };
  return (unsigned short)(enc1(a) | (enc1(b) << 8));
#endif
}
template <bool HI>
__device__ __forceinline__ f32x2 fp8unpack2(unsigned w) {
#if __has_builtin(__builtin_amdgcn_cvt_pk_f32_fp8)
  return __builtin_amdgcn_cvt_pk_f32_fp8((int)w, HI);
#else
  unsigned w2 = HI ? (w >> 16) : w;
  auto dec1 = [](unsigned b) -> float {
    unsigned f = ((b & 0x80u) << 24) | ((b & 0x7fu) << 20);
    return __uint_as_float(f) * 0x1p120f;
  };
  f32x2 r;
  r.x = dec1(w2 & 0xffu);
  r.y = dec1((w2 >> 8) & 0xffu);
  return r;
#endif
}

// ---------- K_PRE: fused [gemm1 | bcount] by block range ----------
__global__ __launch_bounds__(256) void k_pre(const float* __restrict__ x,
    const float* __restrict__ W1, const float* __restrict__ root1,
    const float* __restrict__ bias1,
    unsigned char* __restrict__ XD8, float* __restrict__ XR,
    const int* __restrict__ ei, int* __restrict__ bcnt) {
  __shared__ int h[NBUK];
  int t = threadIdx.x;
  if (blockIdx.x >= NBLK_G1) {
    for (int i = t; i < NBUK; i += 256) h[i] = 0;
    __syncthreads();
    int base = (blockIdx.x - NBLK_G1) * CHUNK;
#pragma unroll
    for (int i = 0; i < 16; ++i) {
      int e = base + i * 256 + t;
      if (e < NE) atomicAdd(&h[ei[NE + e] >> 9], 1);
    }
    __syncthreads();
    for (int i = t; i < NBUK; i += 256)
      if (h[i]) atomicAdd(&bcnt[i], h[i]);
    return;
  }
  int l = t & 63;
  int wv = (blockIdx.x * 256 + t) >> 6;
  int nb = wv * 16;
  if (nb >= NN) return;
  int j16 = l & 15, kg = l >> 4;

  bf16x8 bfrag[3][4];
  const float* wsrc0 = W1;
  const float* wsrc1 = W1 + 2048;
  const float* wsrc2 = root1;
#pragma unroll
  for (int kk = 0; kk < 4; ++kk) {
    int krow = kk * 32 + kg * 8;
#pragma unroll
    for (int b = 0; b < 8; ++b) {
      int o = (krow + b) * 16 + j16;
      bfrag[0][kk][b] = (short)bf16rne(wsrc0[o]);
      bfrag[1][kk][b] = (short)bf16rne(wsrc1[o]);
      bfrag[2][kk][b] = (short)bf16rne(wsrc2[o]);
    }
  }

  f32x4 acc0 = {0.f, 0.f, 0.f, 0.f};
  f32x4 acc1 = {0.f, 0.f, 0.f, 0.f};
  f32x4 acc2 = {0.f, 0.f, 0.f, 0.f};
  const float* xrow = x + (size_t)(nb + j16) * FIN + kg * 8;
#pragma unroll
  for (int kk = 0; kk < 4; ++kk) {
    float4 xa = *(const float4*)(xrow + kk * 32);
    float4 xb = *(const float4*)(xrow + kk * 32 + 4);
    bf16x8 a;
    a[0] = (short)bf16rne(xa.x); a[1] = (short)bf16rne(xa.y);
    a[2] = (short)bf16rne(xa.z); a[3] = (short)bf16rne(xa.w);
    a[4] = (short)bf16rne(xb.x); a[5] = (short)bf16rne(xb.y);
    a[6] = (short)bf16rne(xb.z); a[7] = (short)bf16rne(xb.w);
    acc0 = __builtin_amdgcn_mfma_f32_16x16x32_bf16(a, bfrag[0][kk], acc0, 0, 0, 0);
    acc1 = __builtin_amdgcn_mfma_f32_16x16x32_bf16(a, bfrag[1][kk], acc1, 0, 0, 0);
    acc2 = __builtin_amdgcn_mfma_f32_16x16x32_bf16(a, bfrag[2][kk], acc2, 0, 0, 0);
  }

  float bb = bias1[j16];
#pragma unroll
  for (int r = 0; r < 4; ++r) {
    int n = nb + kg * 4 + r;
    *(unsigned short*)(XD8 + (size_t)n * 32 + j16 * 2) =
        fp8pack2(acc0[r], acc1[r] - acc0[r]);
    XR[(size_t)n * HID + j16] = acc2[r] + bb;
  }
}

__global__ __launch_bounds__(256) void k_bscan(const int* __restrict__ bcnt,
    int* __restrict__ bbase, int* __restrict__ bcur) {
  __shared__ int scn[256];
  int t = threadIdx.x;
  int v = (t < NBUK) ? bcnt[t] : 0;
  scn[t] = v;
  __syncthreads();
  for (int st = 1; st < 256; st <<= 1) {
    int tmp = (t >= st) ? scn[t - st] : 0;
    __syncthreads();
    scn[t] += tmp;
    __syncthreads();
  }
  if (t < NBUK) { int ex = scn[t] - v; bbase[t] = ex; bcur[t] = ex; }
  if (t == NBUK - 1) bbase[NBUK] = scn[t];
}

// Bucketize: bx = (dst&511)<<17 | src ; bu = u quantized to 8 bits
__global__ __launch_bounds__(256) void k_bucketize(const int* __restrict__ ei,
    const float* __restrict__ ea, int* __restrict__ bcur,
    unsigned* __restrict__ bx, unsigned char* __restrict__ bu) {
  __shared__ int lh[NBUK];
  __shared__ int lbase[NBUK];
  __shared__ int gb[NBUK];
  __shared__ int scn[256];
  __shared__ int meta[CHUNK];
  __shared__ unsigned char ubuf[CHUNK];
  __shared__ unsigned char sbkt[CHUNK];
  int t = threadIdx.x;
  for (int i = t; i < NBUK; i += 256) lh[i] = 0;
  __syncthreads();
  int base = blockIdx.x * CHUNK;
  int rk[16], bk[16], mt[16];
  unsigned char uv[16];
#pragma unroll
  for (int i = 0; i < 16; ++i) {
    int e = base + i * 256 + t;
    if (e < NE) {
      int d = ei[NE + e], sv = ei[e];
      int b = d >> 9;
      rk[i] = atomicAdd(&lh[b], 1);
      bk[i] = b;
      mt[i] = ((d & 511) << 17) | sv;
      uv[i] = (unsigned char)__float2int_rn(ea[e] * 255.0f);
    } else bk[i] = -1;
  }
  __syncthreads();
  int v = (t < NBUK) ? lh[t] : 0;
  scn[t] = v;
  __syncthreads();
  for (int st = 1; st < 256; st <<= 1) {
    int tmp = (t >= st) ? scn[t - st] : 0;
    __syncthreads();
    scn[t] += tmp;
    __syncthreads();
  }
  if (t < NBUK) lbase[t] = scn[t] - v;
  int total = scn[255];
  __syncthreads();
  if (t < NBUK && lh[t] > 0) gb[t] = atomicAdd(&bcur[t], lh[t]);
  __syncthreads();
#pragma unroll
  for (int i = 0; i < 16; ++i) {
    if (bk[i] >= 0) {
      int p = lbase[bk[i]] + rk[i];
      meta[p] = mt[i];
      ubuf[p] = uv[i];
      sbkt[p] = (unsigned char)bk[i];
    }
  }
  __syncthreads();
  for (int s = t; s < total; s += 256) {
    int b = sbkt[s];
    int pos = gb[b] + (s - lbase[b]);
    bx[pos] = (unsigned)meta[s];
    bu[pos] = ubuf[s];
  }
}

// CSR: one block per bucket -> off[] (inclusive row-end) + sedge (src | u8<<17)
__global__ __launch_bounds__(512) void k_csr(const unsigned* __restrict__ bx,
    const unsigned char* __restrict__ bu, const int* __restrict__ bbase,
    int* __restrict__ off, unsigned* __restrict__ sedge) {
  __shared__ int cnt[512];
  __shared__ int scn[512];
  __shared__ int cur[512];
  int b = blockIdx.x, t = threadIdx.x;
  int s0 = bbase[b], s1 = bbase[b + 1];
  cnt[t] = 0;
  __syncthreads();
  for (int i = s0 + t; i < s1; i += 512)
    atomicAdd(&cnt[bx[i] >> 17], 1);
  __syncthreads();
  int v = cnt[t];
  scn[t] = v;
  __syncthreads();
  for (int st = 1; st < 512; st <<= 1) {
    int tmp = (t >= st) ? scn[t - st] : 0;
    __syncthreads();
    scn[t] += tmp;
    __syncthreads();
  }
  int n = (b << 9) + t;
  if (n < NN) off[n] = s0 + scn[t];
  cur[t] = s0 + scn[t] - v;
  __syncthreads();
  for (int i = s0 + t; i < s1; i += 512) {
    unsigned r = bx[i];
    int local = r >> 17;
    int pos = atomicAdd(&cur[local], 1);
    sedge[pos] = (r & 131071u) | ((unsigned)bu[i] << 17);
  }
}

// ---------- pull kernels ----------

// Pull pass 1:  Hb[n] = bf16(elu(mean_e(X0[s]+u*D[s]) + XR[n]))
// fp8 XD8 table (3.2 MB, mostly L2-resident). Edge loop unrolled x8 for MLP.
__global__ __launch_bounds__(256) void k_pull1(const int* __restrict__ off,
    const unsigned* __restrict__ sedge, const unsigned char* __restrict__ XD8,
    const float* __restrict__ XR, unsigned* __restrict__ Hb) {
  int tid = blockIdx.x * 256 + threadIdx.x;
  int n = tid >> 2, c = tid & 3;
  if (n >= NN) return;
  int start = (n == 0) ? 0 : off[n - 1];
  int end = off[n];
  float4 acc = make_float4(0.f, 0.f, 0.f, 0.f);
  int i = start;
  for (; i + 8 <= end; i += 8) {
    unsigned se[8];
    uint2 w[8];
#pragma unroll
    for (int q = 0; q < 8; ++q) se[q] = sedge[i + q];
#pragma unroll
    for (int q = 0; q < 8; ++q)
      w[q] = *(const uint2*)(XD8 + (size_t)(se[q] & 131071u) * 32 + c * 8);
#pragma unroll
    for (int q = 0; q < 8; ++q) {
      float u = (float)((se[q] >> 17) & 255u) * (1.0f / 255.0f);
      f32x2 p;
      p = fp8unpack2<false>(w[q].x); acc.x += p.x + u * p.y;
      p = fp8unpack2<true>(w[q].x);  acc.y += p.x + u * p.y;
      p = fp8unpack2<false>(w[q].y); acc.z += p.x + u * p.y;
      p = fp8unpack2<true>(w[q].y);  acc.w += p.x + u * p.y;
    }
  }
  for (; i < end; ++i) {
    unsigned se = sedge[i];
    int s = se & 131071u;
    float u = (float)((se >> 17) & 255u) * (1.0f / 255.0f);
    uint2 w = *(const uint2*)(XD8 + (size_t)s * 32 + c * 8);
    f32x2 p;
    p = fp8unpack2<false>(w.x); acc.x += p.x + u * p.y;
    p = fp8unpack2<true>(w.x);  acc.y += p.x + u * p.y;
    p = fp8unpack2<false>(w.y); acc.z += p.x + u * p.y;
    p = fp8unpack2<true>(w.y);  acc.w += p.x + u * p.y;
  }
  float ic = 1.0f / fmaxf((float)(end - start), 1.0f);
  float4 r = *(const float4*)(XR + (size_t)n * HID + c * 4);
  float4 h;
  h.x = acc.x * ic + r.x;
  h.y = acc.y * ic + r.y;
  h.z = acc.z * ic + r.z;
  h.w = acc.w * ic + r.w;
  h.x = h.x > 0.f ? h.x : expm1f(h.x);
  h.y = h.y > 0.f ? h.y : expm1f(h.y);
  h.z = h.z > 0.f ? h.z : expm1f(h.z);
  h.w = h.w > 0.f ? h.w : expm1f(h.w);
  uint2 hw;
  hw.x = bfpack(h.x, h.y);
  hw.y = bfpack(h.z, h.w);
  *(uint2*)(Hb + (size_t)n * 8 + c * 2) = hw;
}

// Fused pull2 + final. S-trick: accumulate S = sum(h) and A1 = sum(u*h);
// A0 = S - A1 once at the end (halves the inner-loop VALU).
__global__ __launch_bounds__(256) void k_pull2f(const int* __restrict__ off,
    const unsigned* __restrict__ sedge, const unsigned* __restrict__ Hb,
    const float* __restrict__ W2, const float* __restrict__ root2,
    const float* __restrict__ bias2, float* __restrict__ out) {
  __shared__ float a0s[64 * 16];
  __shared__ float a1s[64 * 16];
  __shared__ float ics[64];
  int t = threadIdx.x;
  int nb = blockIdx.x * 64;
  int ln0 = t >> 2, c = t & 3;
  int n = nb + ln0;
  float4 ss = make_float4(0.f, 0.f, 0.f, 0.f);
  float4 a1 = make_float4(0.f, 0.f, 0.f, 0.f);
  int start = 0, end = 0;
  if (n < NN) {
    start = (n == 0) ? 0 : off[n - 1];
    end = off[n];
    int i = start;
    for (; i + 4 <= end; i += 4) {
      unsigned se0 = sedge[i], se1 = sedge[i + 1];
      unsigned se2 = sedge[i + 2], se3 = sedge[i + 3];
      uint2 w0 = *(const uint2*)(Hb + (size_t)(se0 & 131071u) * 8 + c * 2);
      uint2 w1 = *(const uint2*)(Hb + (size_t)(se1 & 131071u) * 8 + c * 2);
      uint2 w2 = *(const uint2*)(Hb + (size_t)(se2 & 131071u) * 8 + c * 2);
      uint2 w3 = *(const uint2*)(Hb + (size_t)(se3 & 131071u) * 8 + c * 2);
      float u0 = (float)((se0 >> 17) & 255u) * (1.0f / 255.0f);
      float u1 = (float)((se1 >> 17) & 255u) * (1.0f / 255.0f);
      float u2 = (float)((se2 >> 17) & 255u) * (1.0f / 255.0f);
      float u3 = (float)((se3 >> 17) & 255u) * (1.0f / 255.0f);
      float h0, h1, h2, h3;
      h0 = bflo(w0.x); h1 = bfhi(w0.x); h2 = bflo(w0.y); h3 = bfhi(w0.y);
      ss.x += h0;  a1.x += u0 * h0;
      ss.y += h1;  a1.y += u0 * h1;
      ss.z += h2;  a1.z += u0 * h2;
      ss.w += h3;  a1.w += u0 * h3;
      h0 = bflo(w1.x); h1 = bfhi(w1.x); h2 = bflo(w1.y); h3 = bfhi(w1.y);
      ss.x += h0;  a1.x += u1 * h0;
      ss.y += h1;  a1.y += u1 * h1;
      ss.z += h2;  a1.z += u1 * h2;
      ss.w += h3;  a1.w += u1 * h3;
      h0 = bflo(w2.x); h1 = bfhi(w2.x); h2 = bflo(w2.y); h3 = bfhi(w2.y);
      ss.x += h0;  a1.x += u2 * h0;
      ss.y += h1;  a1.y += u2 * h1;
      ss.z += h2;  a1.z += u2 * h2;
      ss.w += h3;  a1.w += u2 * h3;
      h0 = bflo(w3.x); h1 = bfhi(w3.x); h2 = bflo(w3.y); h3 = bfhi(w3.y);
      ss.x += h0;  a1.x += u3 * h0;
      ss.y += h1;  a1.y += u3 * h1;
      ss.z += h2;  a1.z += u3 * h2;
      ss.w += h3;  a1.w += u3 * h3;
    }
    for (; i < end; ++i) {
      unsigned se = sedge[i];
      int s = se & 131071u;
      float u = (float)((se >> 17) & 255u) * (1.0f / 255.0f);
      uint2 w = *(const uint2*)(Hb + (size_t)s * 8 + c * 2);
      float h0 = bflo(w.x), h1 = bfhi(w.x), h2 = bflo(w.y), h3 = bfhi(w.y);
      ss.x += h0;  a1.x += u * h0;
      ss.y += h1;  a1.y += u * h1;
      ss.z += h2;  a1.z += u * h2;
      ss.w += h3;  a1.w += u * h3;
    }
  }
  float4 a0;
  a0.x = ss.x - a1.x;
  a0.y = ss.y - a1.y;
  a0.z = ss.z - a1.z;
  a0.w = ss.w - a1.w;
  *(float4*)&a0s[ln0 * 16 + c * 4] = a0;
  *(float4*)&a1s[ln0 * 16 + c * 4] = a1;
  if (c == 0) ics[ln0] = 1.0f / fmaxf((float)(end - start), 1.0f);
  __syncthreads();

  // Phase 2: lane l owns column j; weights in registers; node data from LDS.
  int l = t & 63;
  int wv = t >> 6;                      // wave id 0..3
  int j = (l < NC) ? l : 0;
  float w0r[HID], w1r[HID], rr[HID];
#pragma unroll
  for (int k = 0; k < HID; ++k) {
    w0r[k] = W2[k * NC + j];
    w1r[k] = W2[HID * NC + k * NC + j];
    rr[k]  = root2[k * NC + j];
  }
  float b2 = bias2[j];
#pragma unroll 1
  for (int q = 0; q < 16; ++q) {
    int ln = wv * 16 + q;
    int nn = nb + ln;
    if (nn >= NN) break;
    nn = __builtin_amdgcn_readfirstlane(nn);
    float ic = ics[ln];
    const unsigned* hp = Hb + (size_t)nn * 8;
    float accm = 0.f, accr = 0.f;
#pragma unroll
    for (int k = 0; k < HID; ++k) {
      accm += a0s[ln * 16 + k] * w0r[k];
      accm += a1s[ln * 16 + k] * w1r[k];
      unsigned hw = hp[k >> 1];
      float hk = (k & 1) ? bfhi(hw) : bflo(hw);
      accr += hk * rr[k];
    }
    float logit = accm * ic + accr + b2;
    float mx = (l < NC) ? logit : -INFINITY;
#pragma unroll
    for (int o = 32; o >= 1; o >>= 1) mx = fmaxf(mx, __shfl_xor(mx, o));
    float p = (l < NC) ? __expf(logit - mx) : 0.f;
    float sm = p;
#pragma unroll
    for (int o = 32; o >= 1; o >>= 1) sm += __shfl_xor(sm, o);
    if (l < NC) out[(size_t)nn * NC + l] = logit - mx - __logf(sm);
  }
}

extern "C" void kernel_launch(void* const* d_in, const int* in_sizes, int n_in,
                              void* d_out, int out_size, void* d_ws, size_t ws_size,
                              hipStream_t stream) {
  const float* x     = (const float*)d_in[0];
  const int*   ei    = (const int*)d_in[1];
  const float* ea    = (const float*)d_in[2];
  const float* W1    = (const float*)d_in[3];
  const float* root1 = (const float*)d_in[4];
  const float* bias1 = (const float*)d_in[5];
  const float* W2    = (const float*)d_in[6];
  const float* root2 = (const float*)d_in[7];
  const float* bias2 = (const float*)d_in[8];
  float* out = (float*)d_out;
  char* base = (char*)d_ws;

  // Layout (bytes) — NO aliasing:
  //   [0,       3.2M)  XD8 (u8[NN*32], fp8 X0|D interleaved)
  //   [3.2M,    9.6M)  XR  (f32[NN*16])
  //   [9.6M,   12.8M)  Hb  (u32[NN*8],  bf16 H pairs)
  //   [12.8M,  25.6M)  bx  (u32[NE])
  //   [25.6M,  28.8M)  bu  (u8[NE])
  //   [28.8M,  41.6M)  sedge (u32[NE], src | u8<<17)
  //   [41.6M,  42.0M)  off[NN]
  //   then bcnt[NBUK], bbase[NBUK+1], bcur[NBUK]
  unsigned char* XD8   = (unsigned char*)base;
  float*         XR    = (float*)(base + 3200000);
  unsigned*      Hb    = (unsigned*)(base + 9600000);
  unsigned*      bx    = (unsigned*)(base + 12800000);
  unsigned char* bu    = (unsigned char*)(base + 25600000);
  unsigned*      sedge = (unsigned*)(base + 28800000);
  int*           off   = (int*)(base + 41600000);
  int*           bcnt  = off + NN;
  int*           bbase = bcnt + NBUK;
  int*           bcur  = bbase + NBUK + 1;

  (void)hipMemsetAsync(bcnt, 0, NBUK * sizeof(int), stream);

  k_pre<<<NBLK_G1 + NBLK_BKT, 256, 0, stream>>>(x, W1, root1, bias1, XD8, XR, ei, bcnt);
  k_bscan<<<1, 256, 0, stream>>>(bcnt, bbase, bcur);
  k_bucketize<<<NBLK_BKT, 256, 0, stream>>>(ei, ea, bcur, bx, bu);
  k_csr<<<NBUK, 512, 0, stream>>>(bx, bu, bbase, off, sedge);
  k_pull1<<<(NN * 4 + 255) / 256, 256, 0, stream>>>(off, sedge, XD8, XR, Hb);
  k_pull2f<<<(NN + 63) / 64, 256, 0, stream>>>(off, sedge, Hb, W2, root2, bias2, out);
}

// Round 15
// 199.664 us; speedup vs baseline: 5.7885x; 1.0276x over previous
//
#include <hip/hip_runtime.h>
#include <cstddef>

#define NN 100000
#define NE 3200000
#define FIN 128
#define HID 16
#define NC 40
#define NBUK 196                 // ceil(100000 / 512) node-range buckets
#define CHUNK 4096               // edges per block in bucketing passes
#define NBLK_BKT ((NE + CHUNK - 1) / CHUNK)   // 782
#define NWAVE_G1 (NN / 16)       // 6250 waves, 16 nodes each
#define NBLK_G1 ((NWAVE_G1 + 3) / 4)          // 1563

typedef __attribute__((ext_vector_type(8))) short bf16x8;
typedef __attribute__((ext_vector_type(4))) float f32x4;
typedef __attribute__((ext_vector_type(2))) float f32x2;

// ---- bf16 helpers (RNE pack, cheap unpack) ----
__device__ __forceinline__ unsigned bf16rne(float f) {
  unsigned u = __float_as_uint(f);
  return (u + 0x7fffu + ((u >> 16) & 1u)) >> 16;
}
__device__ __forceinline__ unsigned bfpack(float lo, float hi) {
  return bf16rne(lo) | (bf16rne(hi) << 16);
}
__device__ __forceinline__ float bflo(unsigned w) { return __uint_as_float(w << 16); }
__device__ __forceinline__ float bfhi(unsigned w) { return __uint_as_float(w & 0xffff0000u); }

// ---- fp8 e4m3 helpers ----
__device__ __forceinline__ unsigned short fp8pack2(float a, float b) {
#if __has_builtin(__builtin_amdgcn_cvt_pk_fp8_f32)
  return (unsigned short)__builtin_amdgcn_cvt_pk_fp8_f32(a, b, 0, false);
#else
  auto enc1 = [](float f) -> unsigned {
    float y = f * 0x1p-120f;
    unsigned bb = __float_as_uint(y);
    unsigned s = (bb >> 24) & 0x80u;
    unsigned m = bb & 0x7fffffffu;
    const unsigned maxb = (15u << 23) | (6u << 20);   // 448
    m = m + 0x7ffffu + ((m >> 20) & 1u);              // RNE at bit 20
    if (m > maxb) m = maxb;
    return s | (m >> 20);
  };
  return (unsigned short)(enc1(a) | (enc1(b) << 8));
#endif
}
template <bool HI>
__device__ __forceinline__ f32x2 fp8unpack2(unsigned w) {
#if __has_builtin(__builtin_amdgcn_cvt_pk_f32_fp8)
  return __builtin_amdgcn_cvt_pk_f32_fp8((int)w, HI);
#else
  unsigned w2 = HI ? (w >> 16) : w;
  auto dec1 = [](unsigned b) -> float {
    unsigned f = ((b & 0x80u) << 24) | ((b & 0x7fu) << 20);
    return __uint_as_float(f) * 0x1p120f;
  };
  f32x2 r;
  r.x = dec1(w2 & 0xffu);
  r.y = dec1((w2 >> 8) & 0xffu);
  return r;
#endif
}

// ---------- K_PRE: fused [gemm1 | bcount] by block range ----------
__global__ __launch_bounds__(256) void k_pre(const float* __restrict__ x,
    const float* __restrict__ W1, const float* __restrict__ root1,
    const float* __restrict__ bias1,
    unsigned char* __restrict__ XD8, float* __restrict__ XR,
    const int* __restrict__ ei, int* __restrict__ bcnt) {
  __shared__ int h[NBUK];
  int t = threadIdx.x;
  if (blockIdx.x >= NBLK_G1) {
    for (int i = t; i < NBUK; i += 256) h[i] = 0;
    __syncthreads();
    int base = (blockIdx.x - NBLK_G1) * CHUNK;
#pragma unroll
    for (int i = 0; i < 16; ++i) {
      int e = base + i * 256 + t;
      if (e < NE) atomicAdd(&h[ei[NE + e] >> 9], 1);
    }
    __syncthreads();
    for (int i = t; i < NBUK; i += 256)
      if (h[i]) atomicAdd(&bcnt[i], h[i]);
    return;
  }
  int l = t & 63;
  int wv = (blockIdx.x * 256 + t) >> 6;
  int nb = wv * 16;
  if (nb >= NN) return;
  int j16 = l & 15, kg = l >> 4;

  bf16x8 bfrag[3][4];
  const float* wsrc0 = W1;
  const float* wsrc1 = W1 + 2048;
  const float* wsrc2 = root1;
#pragma unroll
  for (int kk = 0; kk < 4; ++kk) {
    int krow = kk * 32 + kg * 8;
#pragma unroll
    for (int b = 0; b < 8; ++b) {
      int o = (krow + b) * 16 + j16;
      bfrag[0][kk][b] = (short)bf16rne(wsrc0[o]);
      bfrag[1][kk][b] = (short)bf16rne(wsrc1[o]);
      bfrag[2][kk][b] = (short)bf16rne(wsrc2[o]);
    }
  }

  f32x4 acc0 = {0.f, 0.f, 0.f, 0.f};
  f32x4 acc1 = {0.f, 0.f, 0.f, 0.f};
  f32x4 acc2 = {0.f, 0.f, 0.f, 0.f};
  const float* xrow = x + (size_t)(nb + j16) * FIN + kg * 8;
#pragma unroll
  for (int kk = 0; kk < 4; ++kk) {
    float4 xa = *(const float4*)(xrow + kk * 32);
    float4 xb = *(const float4*)(xrow + kk * 32 + 4);
    bf16x8 a;
    a[0] = (short)bf16rne(xa.x); a[1] = (short)bf16rne(xa.y);
    a[2] = (short)bf16rne(xa.z); a[3] = (short)bf16rne(xa.w);
    a[4] = (short)bf16rne(xb.x); a[5] = (short)bf16rne(xb.y);
    a[6] = (short)bf16rne(xb.z); a[7] = (short)bf16rne(xb.w);
    acc0 = __builtin_amdgcn_mfma_f32_16x16x32_bf16(a, bfrag[0][kk], acc0, 0, 0, 0);
    acc1 = __builtin_amdgcn_mfma_f32_16x16x32_bf16(a, bfrag[1][kk], acc1, 0, 0, 0);
    acc2 = __builtin_amdgcn_mfma_f32_16x16x32_bf16(a, bfrag[2][kk], acc2, 0, 0, 0);
  }

  float bb = bias1[j16];
#pragma unroll
  for (int r = 0; r < 4; ++r) {
    int n = nb + kg * 4 + r;
    *(unsigned short*)(XD8 + (size_t)n * 32 + j16 * 2) =
        fp8pack2(acc0[r], acc1[r] - acc0[r]);
    XR[(size_t)n * HID + j16] = acc2[r] + bb;
  }
}

__global__ __launch_bounds__(256) void k_bscan(const int* __restrict__ bcnt,
    int* __restrict__ bbase, int* __restrict__ bcur) {
  __shared__ int scn[256];
  int t = threadIdx.x;
  int v = (t < NBUK) ? bcnt[t] : 0;
  scn[t] = v;
  __syncthreads();
  for (int st = 1; st < 256; st <<= 1) {
    int tmp = (t >= st) ? scn[t - st] : 0;
    __syncthreads();
    scn[t] += tmp;
    __syncthreads();
  }
  if (t < NBUK) { int ex = scn[t] - v; bbase[t] = ex; bcur[t] = ex; }
  if (t == NBUK - 1) bbase[NBUK] = scn[t];
}

// Bucketize: bx = (dst&511)<<17 | src ; bu = u quantized to 8 bits
__global__ __launch_bounds__(256) void k_bucketize(const int* __restrict__ ei,
    const float* __restrict__ ea, int* __restrict__ bcur,
    unsigned* __restrict__ bx, unsigned char* __restrict__ bu) {
  __shared__ int lh[NBUK];
  __shared__ int lbase[NBUK];
  __shared__ int gb[NBUK];
  __shared__ int scn[256];
  __shared__ int meta[CHUNK];
  __shared__ unsigned char ubuf[CHUNK];
  __shared__ unsigned char sbkt[CHUNK];
  int t = threadIdx.x;
  for (int i = t; i < NBUK; i += 256) lh[i] = 0;
  __syncthreads();
  int base = blockIdx.x * CHUNK;
  int rk[16], bk[16], mt[16];
  unsigned char uv[16];
#pragma unroll
  for (int i = 0; i < 16; ++i) {
    int e = base + i * 256 + t;
    if (e < NE) {
      int d = ei[NE + e], sv = ei[e];
      int b = d >> 9;
      rk[i] = atomicAdd(&lh[b], 1);
      bk[i] = b;
      mt[i] = ((d & 511) << 17) | sv;
      uv[i] = (unsigned char)__float2int_rn(ea[e] * 255.0f);
    } else bk[i] = -1;
  }
  __syncthreads();
  int v = (t < NBUK) ? lh[t] : 0;
  scn[t] = v;
  __syncthreads();
  for (int st = 1; st < 256; st <<= 1) {
    int tmp = (t >= st) ? scn[t - st] : 0;
    __syncthreads();
    scn[t] += tmp;
    __syncthreads();
  }
  if (t < NBUK) lbase[t] = scn[t] - v;
  int total = scn[255];
  __syncthreads();
  if (t < NBUK && lh[t] > 0) gb[t] = atomicAdd(&bcur[t], lh[t]);
  __syncthreads();
#pragma unroll
  for (int i = 0; i < 16; ++i) {
    if (bk[i] >= 0) {
      int p = lbase[bk[i]] + rk[i];
      meta[p] = mt[i];
      ubuf[p] = uv[i];
      sbkt[p] = (unsigned char)bk[i];
    }
  }
  __syncthreads();
  for (int s = t; s < total; s += 256) {
    int b = sbkt[s];
    int pos = gb[b] + (s - lbase[b]);
    bx[pos] = (unsigned)meta[s];
    bu[pos] = ubuf[s];
  }
}

// CSR: one block per bucket -> off[] (inclusive row-end) + sedge (src | u8<<17)
__global__ __launch_bounds__(512) void k_csr(const unsigned* __restrict__ bx,
    const unsigned char* __restrict__ bu, const int* __restrict__ bbase,
    int* __restrict__ off, unsigned* __restrict__ sedge) {
  __shared__ int cnt[512];
  __shared__ int scn[512];
  __shared__ int cur[512];
  int b = blockIdx.x, t = threadIdx.x;
  int s0 = bbase[b], s1 = bbase[b + 1];
  cnt[t] = 0;
  __syncthreads();
  for (int i = s0 + t; i < s1; i += 512)
    atomicAdd(&cnt[bx[i] >> 17], 1);
  __syncthreads();
  int v = cnt[t];
  scn[t] = v;
  __syncthreads();
  for (int st = 1; st < 512; st <<= 1) {
    int tmp = (t >= st) ? scn[t - st] : 0;
    __syncthreads();
    scn[t] += tmp;
    __syncthreads();
  }
  int n = (b << 9) + t;
  if (n < NN) off[n] = s0 + scn[t];
  cur[t] = s0 + scn[t] - v;
  __syncthreads();
  for (int i = s0 + t; i < s1; i += 512) {
    unsigned r = bx[i];
    int local = r >> 17;
    int pos = atomicAdd(&cur[local], 1);
    sedge[pos] = (r & 131071u) | ((unsigned)bu[i] << 17);
  }
}

// ---------- pull kernels ----------

// Pull pass 1:  h = elu(mean_e(X0[s]+u*D[s]) + XR[n]); writes bf16 Hb (exact
// path for k_pull2f phase 2) AND fp8 H8 (gather table for phase 1).
__global__ __launch_bounds__(256) void k_pull1(const int* __restrict__ off,
    const unsigned* __restrict__ sedge, const unsigned char* __restrict__ XD8,
    const float* __restrict__ XR, unsigned* __restrict__ Hb,
    unsigned* __restrict__ H8) {
  int tid = blockIdx.x * 256 + threadIdx.x;
  int n = tid >> 2, c = tid & 3;
  if (n >= NN) return;
  int start = (n == 0) ? 0 : off[n - 1];
  int end = off[n];
  float4 acc = make_float4(0.f, 0.f, 0.f, 0.f);
  int i = start;
  for (; i + 8 <= end; i += 8) {
    unsigned se[8];
    uint2 w[8];
#pragma unroll
    for (int q = 0; q < 8; ++q) se[q] = sedge[i + q];
#pragma unroll
    for (int q = 0; q < 8; ++q)
      w[q] = *(const uint2*)(XD8 + (size_t)(se[q] & 131071u) * 32 + c * 8);
#pragma unroll
    for (int q = 0; q < 8; ++q) {
      float u = (float)((se[q] >> 17) & 255u) * (1.0f / 255.0f);
      f32x2 p;
      p = fp8unpack2<false>(w[q].x); acc.x += p.x + u * p.y;
      p = fp8unpack2<true>(w[q].x);  acc.y += p.x + u * p.y;
      p = fp8unpack2<false>(w[q].y); acc.z += p.x + u * p.y;
      p = fp8unpack2<true>(w[q].y);  acc.w += p.x + u * p.y;
    }
  }
  for (; i < end; ++i) {
    unsigned se = sedge[i];
    int s = se & 131071u;
    float u = (float)((se >> 17) & 255u) * (1.0f / 255.0f);
    uint2 w = *(const uint2*)(XD8 + (size_t)s * 32 + c * 8);
    f32x2 p;
    p = fp8unpack2<false>(w.x); acc.x += p.x + u * p.y;
    p = fp8unpack2<true>(w.x);  acc.y += p.x + u * p.y;
    p = fp8unpack2<false>(w.y); acc.z += p.x + u * p.y;
    p = fp8unpack2<true>(w.y);  acc.w += p.x + u * p.y;
  }
  float ic = 1.0f / fmaxf((float)(end - start), 1.0f);
  float4 r = *(const float4*)(XR + (size_t)n * HID + c * 4);
  float4 h;
  h.x = acc.x * ic + r.x;
  h.y = acc.y * ic + r.y;
  h.z = acc.z * ic + r.z;
  h.w = acc.w * ic + r.w;
  h.x = h.x > 0.f ? h.x : expm1f(h.x);
  h.y = h.y > 0.f ? h.y : expm1f(h.y);
  h.z = h.z > 0.f ? h.z : expm1f(h.z);
  h.w = h.w > 0.f ? h.w : expm1f(h.w);
  uint2 hw;
  hw.x = bfpack(h.x, h.y);
  hw.y = bfpack(h.z, h.w);
  *(uint2*)(Hb + (size_t)n * 8 + c * 2) = hw;
  H8[(size_t)n * 4 + c] =
      (unsigned)fp8pack2(h.x, h.y) | ((unsigned)fp8pack2(h.z, h.w) << 16);
}

// Fused pull2 + final. Phase 1 gathers from the fp8 H8 table: ONE dword per
// edge per thread (was uint2 from bf16 Hb). S-trick: A0 = S - A1 at the end.
__global__ __launch_bounds__(256) void k_pull2f(const int* __restrict__ off,
    const unsigned* __restrict__ sedge, const unsigned* __restrict__ H8,
    const unsigned* __restrict__ Hb, const float* __restrict__ W2,
    const float* __restrict__ root2, const float* __restrict__ bias2,
    float* __restrict__ out) {
  __shared__ float a0s[64 * 16];
  __shared__ float a1s[64 * 16];
  __shared__ float ics[64];
  int t = threadIdx.x;
  int nb = blockIdx.x * 64;
  int ln0 = t >> 2, c = t & 3;
  int n = nb + ln0;
  float4 ss = make_float4(0.f, 0.f, 0.f, 0.f);
  float4 a1 = make_float4(0.f, 0.f, 0.f, 0.f);
  int start = 0, end = 0;
  if (n < NN) {
    start = (n == 0) ? 0 : off[n - 1];
    end = off[n];
    int i = start;
    for (; i + 8 <= end; i += 8) {
      unsigned se[8], w[8];
#pragma unroll
      for (int q = 0; q < 8; ++q) se[q] = sedge[i + q];
#pragma unroll
      for (int q = 0; q < 8; ++q)
        w[q] = H8[(size_t)(se[q] & 131071u) * 4 + c];
#pragma unroll
      for (int q = 0; q < 8; ++q) {
        float u = (float)((se[q] >> 17) & 255u) * (1.0f / 255.0f);
        f32x2 p;
        p = fp8unpack2<false>(w[q]);
        ss.x += p.x;  a1.x += u * p.x;
        ss.y += p.y;  a1.y += u * p.y;
        p = fp8unpack2<true>(w[q]);
        ss.z += p.x;  a1.z += u * p.x;
        ss.w += p.y;  a1.w += u * p.y;
      }
    }
    for (; i < end; ++i) {
      unsigned se = sedge[i];
      int s = se & 131071u;
      float u = (float)((se >> 17) & 255u) * (1.0f / 255.0f);
      unsigned w = H8[(size_t)s * 4 + c];
      f32x2 p;
      p = fp8unpack2<false>(w);
      ss.x += p.x;  a1.x += u * p.x;
      ss.y += p.y;  a1.y += u * p.y;
      p = fp8unpack2<true>(w);
      ss.z += p.x;  a1.z += u * p.x;
      ss.w += p.y;  a1.w += u * p.y;
    }
  }
  float4 a0;
  a0.x = ss.x - a1.x;
  a0.y = ss.y - a1.y;
  a0.z = ss.z - a1.z;
  a0.w = ss.w - a1.w;
  *(float4*)&a0s[ln0 * 16 + c * 4] = a0;
  *(float4*)&a1s[ln0 * 16 + c * 4] = a1;
  if (c == 0) ics[ln0] = 1.0f / fmaxf((float)(end - start), 1.0f);
  __syncthreads();

  // Phase 2: lane l owns column j; weights in registers; node data from LDS
  // (A0/A1) and bf16 Hb (root term — exact path).
  int l = t & 63;
  int wv = t >> 6;                      // wave id 0..3
  int j = (l < NC) ? l : 0;
  float w0r[HID], w1r[HID], rr[HID];
#pragma unroll
  for (int k = 0; k < HID; ++k) {
    w0r[k] = W2[k * NC + j];
    w1r[k] = W2[HID * NC + k * NC + j];
    rr[k]  = root2[k * NC + j];
  }
  float b2 = bias2[j];
#pragma unroll 1
  for (int q = 0; q < 16; ++q) {
    int ln = wv * 16 + q;
    int nn = nb + ln;
    if (nn >= NN) break;
    nn = __builtin_amdgcn_readfirstlane(nn);
    float ic = ics[ln];
    const unsigned* hp = Hb + (size_t)nn * 8;
    float accm = 0.f, accr = 0.f;
#pragma unroll
    for (int k = 0; k < HID; ++k) {
      accm += a0s[ln * 16 + k] * w0r[k];
      accm += a1s[ln * 16 + k] * w1r[k];
      unsigned hw = hp[k >> 1];
      float hk = (k & 1) ? bfhi(hw) : bflo(hw);
      accr += hk * rr[k];
    }
    float logit = accm * ic + accr + b2;
    float mx = (l < NC) ? logit : -INFINITY;
#pragma unroll
    for (int o = 32; o >= 1; o >>= 1) mx = fmaxf(mx, __shfl_xor(mx, o));
    float p = (l < NC) ? __expf(logit - mx) : 0.f;
    float sm = p;
#pragma unroll
    for (int o = 32; o >= 1; o >>= 1) sm += __shfl_xor(sm, o);
    if (l < NC) out[(size_t)nn * NC + l] = logit - mx - __logf(sm);
  }
}

extern "C" void kernel_launch(void* const* d_in, const int* in_sizes, int n_in,
                              void* d_out, int out_size, void* d_ws, size_t ws_size,
                              hipStream_t stream) {
  const float* x     = (const float*)d_in[0];
  const int*   ei    = (const int*)d_in[1];
  const float* ea    = (const float*)d_in[2];
  const float* W1    = (const float*)d_in[3];
  const float* root1 = (const float*)d_in[4];
  const float* bias1 = (const float*)d_in[5];
  const float* W2    = (const float*)d_in[6];
  const float* root2 = (const float*)d_in[7];
  const float* bias2 = (const float*)d_in[8];
  float* out = (float*)d_out;
  char* base = (char*)d_ws;

  // Layout (bytes) — NO aliasing:
  //   [0,       3.2M)  XD8 (u8[NN*32], fp8 X0|D interleaved)
  //   [3.2M,    9.6M)  XR  (f32[NN*16])
  //   [9.6M,   12.8M)  Hb  (u32[NN*8],  bf16 H pairs)
  //   [12.8M,  14.4M)  H8  (u32[NN*4],  fp8 H, 16B/node)
  //   [14.4M,  27.2M)  bx  (u32[NE])
  //   [27.2M,  30.4M)  bu  (u8[NE])
  //   [30.4M,  43.2M)  sedge (u32[NE], src | u8<<17)
  //   [43.2M,  43.6M)  off[NN]
  //   then bcnt[NBUK], bbase[NBUK+1], bcur[NBUK]
  unsigned char* XD8   = (unsigned char*)base;
  float*         XR    = (float*)(base + 3200000);
  unsigned*      Hb    = (unsigned*)(base + 9600000);
  unsigned*      H8    = (unsigned*)(base + 12800000);
  unsigned*      bx    = (unsigned*)(base + 14400000);
  unsigned char* bu    = (unsigned char*)(base + 27200000);
  unsigned*      sedge = (unsigned*)(base + 30400000);
  int*           off   = (int*)(base + 43200000);
  int*           bcnt  = off + NN;
  int*           bbase = bcnt + NBUK;
  int*           bcur  = bbase + NBUK + 1;

  (void)hipMemsetAsync(bcnt, 0, NBUK * sizeof(int), stream);

  k_pre<<<NBLK_G1 + NBLK_BKT, 256, 0, stream>>>(x, W1, root1, bias1, XD8, XR, ei, bcnt);
  k_bscan<<<1, 256, 0, stream>>>(bcnt, bbase, bcur);
  k_bucketize<<<NBLK_BKT, 256, 0, stream>>>(ei, ea, bcur, bx, bu);
  k_csr<<<NBUK, 512, 0, stream>>>(bx, bu, bbase, off, sedge);
  k_pull1<<<(NN * 4 + 255) / 256, 256, 0, stream>>>(off, sedge, XD8, XR, Hb, H8);
  k_pull2f<<<(NN + 63) / 64, 256, 0, stream>>>(off, sedge, H8, Hb, W2, root2, bias2, out);
}

// Round 16
// 189.883 us; speedup vs baseline: 6.0867x; 1.0515x over previous
//
#include <hip/hip_runtime.h>
#include <cstddef>

#define NN 100000
#define NE 3200000
#define FIN 128
#define HID 16
#define NC 40
#define NBUK 196                 // ceil(100000 / 512) node-range buckets
#define CHUNK 4096               // edges per block in bucketing passes
#define NBLK_BKT ((NE + CHUNK - 1) / CHUNK)   // 782
#define NWAVE_G1 (NN / 16)       // 6250 waves, 16 nodes each
#define NBLK_G1 ((NWAVE_G1 + 3) / 4)          // 1563

typedef __attribute__((ext_vector_type(8))) short bf16x8;
typedef __attribute__((ext_vector_type(4))) float f32x4;
typedef __attribute__((ext_vector_type(2))) float f32x2;

// ---- bf16 helpers (RNE pack, cheap unpack) ----
__device__ __forceinline__ unsigned bf16rne(float f) {
  unsigned u = __float_as_uint(f);
  return (u + 0x7fffu + ((u >> 16) & 1u)) >> 16;
}
__device__ __forceinline__ unsigned bfpack(float lo, float hi) {
  return bf16rne(lo) | (bf16rne(hi) << 16);
}
__device__ __forceinline__ float bflo(unsigned w) { return __uint_as_float(w << 16); }
__device__ __forceinline__ float bfhi(unsigned w) { return __uint_as_float(w & 0xffff0000u); }

// ---- fp8 e4m3 helpers ----
__device__ __forceinline__ unsigned short fp8pack2(float a, float b) {
#if __has_builtin(__builtin_amdgcn_cvt_pk_fp8_f32)
  return (unsigned short)__builtin_amdgcn_cvt_pk_fp8_f32(a, b, 0, false);
#else
  auto enc1 = [](float f) -> unsigned {
    float y = f * 0x1p-120f;
    unsigned bb = __float_as_uint(y);
    unsigned s = (bb >> 24) & 0x80u;
    unsigned m = bb & 0x7fffffffu;
    const unsigned maxb = (15u << 23) | (6u << 20);   // 448
    m = m + 0x7ffffu + ((m >> 20) & 1u);              // RNE at bit 20
    if (m > maxb) m = maxb;
    return s | (m >> 20);
  };
  return (unsigned short)(enc1(a) | (enc1(b) << 8));
#endif
}
template <bool HI>
__device__ __forceinline__ f32x2 fp8unpack2(unsigned w) {
#if __has_builtin(__builtin_amdgcn_cvt_pk_f32_fp8)
  return __builtin_amdgcn_cvt_pk_f32_fp8((int)w, HI);
#else
  unsigned w2 = HI ? (w >> 16) : w;
  auto dec1 = [](unsigned b) -> float {
    unsigned f = ((b & 0x80u) << 24) | ((b & 0x7fu) << 20);
    return __uint_as_float(f) * 0x1p120f;
  };
  f32x2 r;
  r.x = dec1(w2 & 0xffu);
  r.y = dec1((w2 >> 8) & 0xffu);
  return r;
#endif
}

// ---------- K_PRE: fused [gemm1 | bcount] by block range ----------
__global__ __launch_bounds__(256) void k_pre(const float* __restrict__ x,
    const float* __restrict__ W1, const float* __restrict__ root1,
    const float* __restrict__ bias1,
    unsigned char* __restrict__ XD8, float* __restrict__ XR,
    const int* __restrict__ ei, int* __restrict__ bcnt) {
  __shared__ int h[NBUK];
  int t = threadIdx.x;
  if (blockIdx.x >= NBLK_G1) {
    for (int i = t; i < NBUK; i += 256) h[i] = 0;
    __syncthreads();
    int base = (blockIdx.x - NBLK_G1) * CHUNK;
#pragma unroll
    for (int i = 0; i < 16; ++i) {
      int e = base + i * 256 + t;
      if (e < NE) atomicAdd(&h[ei[NE + e] >> 9], 1);
    }
    __syncthreads();
    for (int i = t; i < NBUK; i += 256)
      if (h[i]) atomicAdd(&bcnt[i], h[i]);
    return;
  }
  int l = t & 63;
  int wv = (blockIdx.x * 256 + t) >> 6;
  int nb = wv * 16;
  if (nb >= NN) return;
  int j16 = l & 15, kg = l >> 4;

  bf16x8 bfrag[3][4];
  const float* wsrc0 = W1;
  const float* wsrc1 = W1 + 2048;
  const float* wsrc2 = root1;
#pragma unroll
  for (int kk = 0; kk < 4; ++kk) {
    int krow = kk * 32 + kg * 8;
#pragma unroll
    for (int b = 0; b < 8; ++b) {
      int o = (krow + b) * 16 + j16;
      bfrag[0][kk][b] = (short)bf16rne(wsrc0[o]);
      bfrag[1][kk][b] = (short)bf16rne(wsrc1[o]);
      bfrag[2][kk][b] = (short)bf16rne(wsrc2[o]);
    }
  }

  f32x4 acc0 = {0.f, 0.f, 0.f, 0.f};
  f32x4 acc1 = {0.f, 0.f, 0.f, 0.f};
  f32x4 acc2 = {0.f, 0.f, 0.f, 0.f};
  const float* xrow = x + (size_t)(nb + j16) * FIN + kg * 8;
#pragma unroll
  for (int kk = 0; kk < 4; ++kk) {
    float4 xa = *(const float4*)(xrow + kk * 32);
    float4 xb = *(const float4*)(xrow + kk * 32 + 4);
    bf16x8 a;
    a[0] = (short)bf16rne(xa.x); a[1] = (short)bf16rne(xa.y);
    a[2] = (short)bf16rne(xa.z); a[3] = (short)bf16rne(xa.w);
    a[4] = (short)bf16rne(xb.x); a[5] = (short)bf16rne(xb.y);
    a[6] = (short)bf16rne(xb.z); a[7] = (short)bf16rne(xb.w);
    acc0 = __builtin_amdgcn_mfma_f32_16x16x32_bf16(a, bfrag[0][kk], acc0, 0, 0, 0);
    acc1 = __builtin_amdgcn_mfma_f32_16x16x32_bf16(a, bfrag[1][kk], acc1, 0, 0, 0);
    acc2 = __builtin_amdgcn_mfma_f32_16x16x32_bf16(a, bfrag[2][kk], acc2, 0, 0, 0);
  }

  float bb = bias1[j16];
#pragma unroll
  for (int r = 0; r < 4; ++r) {
    int n = nb + kg * 4 + r;
    *(unsigned short*)(XD8 + (size_t)n * 32 + j16 * 2) =
        fp8pack2(acc0[r], acc1[r] - acc0[r]);
    XR[(size_t)n * HID + j16] = acc2[r] + bb;
  }
}

__global__ __launch_bounds__(256) void k_bscan(const int* __restrict__ bcnt,
    int* __restrict__ bbase, int* __restrict__ bcur) {
  __shared__ int scn[256];
  int t = threadIdx.x;
  int v = (t < NBUK) ? bcnt[t] : 0;
  scn[t] = v;
  __syncthreads();
  for (int st = 1; st < 256; st <<= 1) {
    int tmp = (t >= st) ? scn[t - st] : 0;
    __syncthreads();
    scn[t] += tmp;
    __syncthreads();
  }
  if (t < NBUK) { int ex = scn[t] - v; bbase[t] = ex; bcur[t] = ex; }
  if (t == NBUK - 1) bbase[NBUK] = scn[t];
}

// Bucketize: bx = (dst&511)<<17 | src ; bu = u quantized to 8 bits
__global__ __launch_bounds__(256) void k_bucketize(const int* __restrict__ ei,
    const float* __restrict__ ea, int* __restrict__ bcur,
    unsigned* __restrict__ bx, unsigned char* __restrict__ bu) {
  __shared__ int lh[NBUK];
  __shared__ int lbase[NBUK];
  __shared__ int gb[NBUK];
  __shared__ int scn[256];
  __shared__ int meta[CHUNK];
  __shared__ unsigned char ubuf[CHUNK];
  __shared__ unsigned char sbkt[CHUNK];
  int t = threadIdx.x;
  for (int i = t; i < NBUK; i += 256) lh[i] = 0;
  __syncthreads();
  int base = blockIdx.x * CHUNK;
  int rk[16], bk[16], mt[16];
  unsigned char uv[16];
#pragma unroll
  for (int i = 0; i < 16; ++i) {
    int e = base + i * 256 + t;
    if (e < NE) {
      int d = ei[NE + e], sv = ei[e];
      int b = d >> 9;
      rk[i] = atomicAdd(&lh[b], 1);
      bk[i] = b;
      mt[i] = ((d & 511) << 17) | sv;
      uv[i] = (unsigned char)__float2int_rn(ea[e] * 255.0f);
    } else bk[i] = -1;
  }
  __syncthreads();
  int v = (t < NBUK) ? lh[t] : 0;
  scn[t] = v;
  __syncthreads();
  for (int st = 1; st < 256; st <<= 1) {
    int tmp = (t >= st) ? scn[t - st] : 0;
    __syncthreads();
    scn[t] += tmp;
    __syncthreads();
  }
  if (t < NBUK) lbase[t] = scn[t] - v;
  int total = scn[255];
  __syncthreads();
  if (t < NBUK && lh[t] > 0) gb[t] = atomicAdd(&bcur[t], lh[t]);
  __syncthreads();
#pragma unroll
  for (int i = 0; i < 16; ++i) {
    if (bk[i] >= 0) {
      int p = lbase[bk[i]] + rk[i];
      meta[p] = mt[i];
      ubuf[p] = uv[i];
      sbkt[p] = (unsigned char)bk[i];
    }
  }
  __syncthreads();
  for (int s = t; s < total; s += 256) {
    int b = sbkt[s];
    int pos = gb[b] + (s - lbase[b]);
    bx[pos] = (unsigned)meta[s];
    bu[pos] = ubuf[s];
  }
}

// CSR: one block per bucket -> off[] (inclusive row-end) + sedge (src | u8<<17)
__global__ __launch_bounds__(512) void k_csr(const unsigned* __restrict__ bx,
    const unsigned char* __restrict__ bu, const int* __restrict__ bbase,
    int* __restrict__ off, unsigned* __restrict__ sedge) {
  __shared__ int cnt[512];
  __shared__ int scn[512];
  __shared__ int cur[512];
  int b = blockIdx.x, t = threadIdx.x;
  int s0 = bbase[b], s1 = bbase[b + 1];
  cnt[t] = 0;
  __syncthreads();
  for (int i = s0 + t; i < s1; i += 512)
    atomicAdd(&cnt[bx[i] >> 17], 1);
  __syncthreads();
  int v = cnt[t];
  scn[t] = v;
  __syncthreads();
  for (int st = 1; st < 512; st <<= 1) {
    int tmp = (t >= st) ? scn[t - st] : 0;
    __syncthreads();
    scn[t] += tmp;
    __syncthreads();
  }
  int n = (b << 9) + t;
  if (n < NN) off[n] = s0 + scn[t];
  cur[t] = s0 + scn[t] - v;
  __syncthreads();
  for (int i = s0 + t; i < s1; i += 512) {
    unsigned r = bx[i];
    int local = r >> 17;
    int pos = atomicAdd(&cur[local], 1);
    sedge[pos] = (r & 131071u) | ((unsigned)bu[i] << 17);
  }
}

// ---------- pull kernels ----------

// Pull pass 1: 8 threads/node = 4-channel slice (c) x 2 edge-halves (half).
// Each thread gathers uint2 from fp8 XD8 for its half's edges; halves combine
// via shfl_xor(4). Writes bf16 Hb + fp8 H8.
__global__ __launch_bounds__(256) void k_pull1(const int* __restrict__ off,
    const unsigned* __restrict__ sedge, const unsigned char* __restrict__ XD8,
    const float* __restrict__ XR, unsigned* __restrict__ Hb,
    unsigned* __restrict__ H8) {
  int tid = blockIdx.x * 256 + threadIdx.x;
  int n = tid >> 3, c = tid & 3, half = (tid >> 2) & 1;
  if (n >= NN) return;
  int start = (n == 0) ? 0 : off[n - 1];
  int end = off[n];
  int mid = start + ((end - start + 1) >> 1);
  int lo = half ? mid : start;
  int hi = half ? end : mid;
  float4 acc = make_float4(0.f, 0.f, 0.f, 0.f);
  int i = lo;
  for (; i + 8 <= hi; i += 8) {
    unsigned se[8];
    uint2 w[8];
#pragma unroll
    for (int q = 0; q < 8; ++q) se[q] = sedge[i + q];
#pragma unroll
    for (int q = 0; q < 8; ++q)
      w[q] = *(const uint2*)(XD8 + (size_t)(se[q] & 131071u) * 32 + c * 8);
#pragma unroll
    for (int q = 0; q < 8; ++q) {
      float u = (float)((se[q] >> 17) & 255u) * (1.0f / 255.0f);
      f32x2 p;
      p = fp8unpack2<false>(w[q].x); acc.x += p.x + u * p.y;
      p = fp8unpack2<true>(w[q].x);  acc.y += p.x + u * p.y;
      p = fp8unpack2<false>(w[q].y); acc.z += p.x + u * p.y;
      p = fp8unpack2<true>(w[q].y);  acc.w += p.x + u * p.y;
    }
  }
  for (; i < hi; ++i) {
    unsigned se = sedge[i];
    int s = se & 131071u;
    float u = (float)((se >> 17) & 255u) * (1.0f / 255.0f);
    uint2 w = *(const uint2*)(XD8 + (size_t)s * 32 + c * 8);
    f32x2 p;
    p = fp8unpack2<false>(w.x); acc.x += p.x + u * p.y;
    p = fp8unpack2<true>(w.x);  acc.y += p.x + u * p.y;
    p = fp8unpack2<false>(w.y); acc.z += p.x + u * p.y;
    p = fp8unpack2<true>(w.y);  acc.w += p.x + u * p.y;
  }
  // combine edge-halves (partner lane differs in tid bit 2, same n and c)
  acc.x += __shfl_xor(acc.x, 4);
  acc.y += __shfl_xor(acc.y, 4);
  acc.z += __shfl_xor(acc.z, 4);
  acc.w += __shfl_xor(acc.w, 4);
  if (half) return;
  float ic = 1.0f / fmaxf((float)(end - start), 1.0f);
  float4 r = *(const float4*)(XR + (size_t)n * HID + c * 4);
  float4 h;
  h.x = acc.x * ic + r.x;
  h.y = acc.y * ic + r.y;
  h.z = acc.z * ic + r.z;
  h.w = acc.w * ic + r.w;
  h.x = h.x > 0.f ? h.x : expm1f(h.x);
  h.y = h.y > 0.f ? h.y : expm1f(h.y);
  h.z = h.z > 0.f ? h.z : expm1f(h.z);
  h.w = h.w > 0.f ? h.w : expm1f(h.w);
  uint2 hw;
  hw.x = bfpack(h.x, h.y);
  hw.y = bfpack(h.z, h.w);
  *(uint2*)(Hb + (size_t)n * 8 + c * 2) = hw;
  H8[(size_t)n * 4 + c] =
      (unsigned)fp8pack2(h.x, h.y) | ((unsigned)fp8pack2(h.z, h.w) << 16);
}

// Fused pull2 + final. Phase 1: 8 threads/node (4-ch slice x 2 edge-halves),
// one dword gather per edge-thread from fp8 H8; halves combine via shfl_xor(4).
// Phase 2: W2 matvec + log_softmax from LDS. Block = 32 nodes.
__global__ __launch_bounds__(256) void k_pull2f(const int* __restrict__ off,
    const unsigned* __restrict__ sedge, const unsigned* __restrict__ H8,
    const unsigned* __restrict__ Hb, const float* __restrict__ W2,
    const float* __restrict__ root2, const float* __restrict__ bias2,
    float* __restrict__ out) {
  __shared__ float a0s[32 * 16];
  __shared__ float a1s[32 * 16];
  __shared__ float ics[32];
  int t = threadIdx.x;
  int nb = blockIdx.x * 32;
  int ln0 = t >> 3, c = t & 3, half = (t >> 2) & 1;
  int n = nb + ln0;
  float4 ss = make_float4(0.f, 0.f, 0.f, 0.f);
  float4 a1 = make_float4(0.f, 0.f, 0.f, 0.f);
  int start = 0, end = 0;
  if (n < NN) {
    start = (n == 0) ? 0 : off[n - 1];
    end = off[n];
    int mid = start + ((end - start + 1) >> 1);
    int lo = half ? mid : start;
    int hi = half ? end : mid;
    int i = lo;
    for (; i + 8 <= hi; i += 8) {
      unsigned se[8], w[8];
#pragma unroll
      for (int q = 0; q < 8; ++q) se[q] = sedge[i + q];
#pragma unroll
      for (int q = 0; q < 8; ++q)
        w[q] = H8[(size_t)(se[q] & 131071u) * 4 + c];
#pragma unroll
      for (int q = 0; q < 8; ++q) {
        float u = (float)((se[q] >> 17) & 255u) * (1.0f / 255.0f);
        f32x2 p;
        p = fp8unpack2<false>(w[q]);
        ss.x += p.x;  a1.x += u * p.x;
        ss.y += p.y;  a1.y += u * p.y;
        p = fp8unpack2<true>(w[q]);
        ss.z += p.x;  a1.z += u * p.x;
        ss.w += p.y;  a1.w += u * p.y;
      }
    }
    for (; i < hi; ++i) {
      unsigned se = sedge[i];
      int s = se & 131071u;
      float u = (float)((se >> 17) & 255u) * (1.0f / 255.0f);
      unsigned w = H8[(size_t)s * 4 + c];
      f32x2 p;
      p = fp8unpack2<false>(w);
      ss.x += p.x;  a1.x += u * p.x;
      ss.y += p.y;  a1.y += u * p.y;
      p = fp8unpack2<true>(w);
      ss.z += p.x;  a1.z += u * p.x;
      ss.w += p.y;  a1.w += u * p.y;
    }
  }
  // combine edge-halves
  ss.x += __shfl_xor(ss.x, 4);
  ss.y += __shfl_xor(ss.y, 4);
  ss.z += __shfl_xor(ss.z, 4);
  ss.w += __shfl_xor(ss.w, 4);
  a1.x += __shfl_xor(a1.x, 4);
  a1.y += __shfl_xor(a1.y, 4);
  a1.z += __shfl_xor(a1.z, 4);
  a1.w += __shfl_xor(a1.w, 4);
  if (half == 0) {
    float4 a0;
    a0.x = ss.x - a1.x;
    a0.y = ss.y - a1.y;
    a0.z = ss.z - a1.z;
    a0.w = ss.w - a1.w;
    *(float4*)&a0s[ln0 * 16 + c * 4] = a0;
    *(float4*)&a1s[ln0 * 16 + c * 4] = a1;
    if (c == 0) ics[ln0] = 1.0f / fmaxf((float)(end - start), 1.0f);
  }
  __syncthreads();

  // Phase 2: lane l owns column j; weights in registers; node data from LDS
  // (A0/A1) and bf16 Hb (root term — exact path).
  int l = t & 63;
  int wv = t >> 6;                      // wave id 0..3, handles 8 nodes each
  int j = (l < NC) ? l : 0;
  float w0r[HID], w1r[HID], rr[HID];
#pragma unroll
  for (int k = 0; k < HID; ++k) {
    w0r[k] = W2[k * NC + j];
    w1r[k] = W2[HID * NC + k * NC + j];
    rr[k]  = root2[k * NC + j];
  }
  float b2 = bias2[j];
#pragma unroll 1
  for (int q = 0; q < 8; ++q) {
    int ln = wv * 8 + q;
    int nn = nb + ln;
    if (nn >= NN) break;
    nn = __builtin_amdgcn_readfirstlane(nn);
    float ic = ics[ln];
    const unsigned* hp = Hb + (size_t)nn * 8;
    float accm = 0.f, accr = 0.f;
#pragma unroll
    for (int k = 0; k < HID; ++k) {
      accm += a0s[ln * 16 + k] * w0r[k];
      accm += a1s[ln * 16 + k] * w1r[k];
      unsigned hw = hp[k >> 1];
      float hk = (k & 1) ? bfhi(hw) : bflo(hw);
      accr += hk * rr[k];
    }
    float logit = accm * ic + accr + b2;
    float mx = (l < NC) ? logit : -INFINITY;
#pragma unroll
    for (int o = 32; o >= 1; o >>= 1) mx = fmaxf(mx, __shfl_xor(mx, o));
    float p = (l < NC) ? __expf(logit - mx) : 0.f;
    float sm = p;
#pragma unroll
    for (int o = 32; o >= 1; o >>= 1) sm += __shfl_xor(sm, o);
    if (l < NC) out[(size_t)nn * NC + l] = logit - mx - __logf(sm);
  }
}

extern "C" void kernel_launch(void* const* d_in, const int* in_sizes, int n_in,
                              void* d_out, int out_size, void* d_ws, size_t ws_size,
                              hipStream_t stream) {
  const float* x     = (const float*)d_in[0];
  const int*   ei    = (const int*)d_in[1];
  const float* ea    = (const float*)d_in[2];
  const float* W1    = (const float*)d_in[3];
  const float* root1 = (const float*)d_in[4];
  const float* bias1 = (const float*)d_in[5];
  const float* W2    = (const float*)d_in[6];
  const float* root2 = (const float*)d_in[7];
  const float* bias2 = (const float*)d_in[8];
  float* out = (float*)d_out;
  char* base = (char*)d_ws;

  // Layout (bytes) — NO aliasing:
  //   [0,       3.2M)  XD8 (u8[NN*32], fp8 X0|D interleaved)
  //   [3.2M,    9.6M)  XR  (f32[NN*16])
  //   [9.6M,   12.8M)  Hb  (u32[NN*8],  bf16 H pairs)
  //   [12.8M,  14.4M)  H8  (u32[NN*4],  fp8 H, 16B/node)
  //   [14.4M,  27.2M)  bx  (u32[NE])
  //   [27.2M,  30.4M)  bu  (u8[NE])
  //   [30.4M,  43.2M)  sedge (u32[NE], src | u8<<17)
  //   [43.2M,  43.6M)  off[NN]
  //   then bcnt[NBUK], bbase[NBUK+1], bcur[NBUK]
  unsigned char* XD8   = (unsigned char*)base;
  float*         XR    = (float*)(base + 3200000);
  unsigned*      Hb    = (unsigned*)(base + 9600000);
  unsigned*      H8    = (unsigned*)(base + 12800000);
  unsigned*      bx    = (unsigned*)(base + 14400000);
  unsigned char* bu    = (unsigned char*)(base + 27200000);
  unsigned*      sedge = (unsigned*)(base + 30400000);
  int*           off   = (int*)(base + 43200000);
  int*           bcnt  = off + NN;
  int*           bbase = bcnt + NBUK;
  int*           bcur  = bbase + NBUK + 1;

  (void)hipMemsetAsync(bcnt, 0, NBUK * sizeof(int), stream);

  k_pre<<<NBLK_G1 + NBLK_BKT, 256, 0, stream>>>(x, W1, root1, bias1, XD8, XR, ei, bcnt);
  k_bscan<<<1, 256, 0, stream>>>(bcnt, bbase, bcur);
  k_bucketize<<<NBLK_BKT, 256, 0, stream>>>(ei, ea, bcur, bx, bu);
  k_csr<<<NBUK, 512, 0, stream>>>(bx, bu, bbase, off, sedge);
  k_pull1<<<(NN * 8 + 255) / 256, 256, 0, stream>>>(off, sedge, XD8, XR, Hb, H8);
  k_pull2f<<<(NN + 31) / 32, 256, 0, stream>>>(off, sedge, H8, Hb, W2, root2, bias2, out);
}